// Round 16
// baseline (484.027 us; speedup 1.0000x reference)
//
#include <hip/hip_runtime.h>
#include <math.h>

#define T_TOKENS 16384
#define HID      4096
#define NEXP     256
#define NGROUP   8
#define GSIZE    32
#define TOPKG    4
#define TOPK     8
#define RSCALE   2.5f

#define TAU   1.5e-5f    // expert-score margin (R13-R15-validated, 9 sigma)
#define TAUG  2.5e-5f    // group-score margin  (R13-R15-validated)

// ---- split-K GEMM config (R9/R14-validated) ----
#define BM     64
#define BK     32
#define SPLITK 4
#define KSPAN  (HID / SPLITK)    // 1024
#define NKS    (KSPAN / BK)      // 32 K-steps per block
#define NSG    (HID / BK)        // 128 global K-steps

// LDS staging (ushort units), UNPADDED frag-major (R9-validated)
#define A_HI   0
#define A_LO   2048
#define B_HI   4096
#define B_LO   12288
#define STG_TOT 20480            // 40 KB -> 4 blocks/CU

#define WQ_LIMB (NSG * 8192)
#define RT_TOK 16                // route tokens/block (R14-validated)
#define RT_STR 260               // Lg row stride (16B-aligned, 2-way banks on scan)

typedef __attribute__((ext_vector_type(8))) short bf16x8;
typedef __attribute__((ext_vector_type(4))) float f32x4;

__device__ __forceinline__ int stoffA(int r, int q) {
    return (r >> 4) * 512 + (q >> 1) * 128 + (r & 15) * 8 + (q & 1) * 4;
}
__device__ __forceinline__ int froffL(int lane) {
    return (lane >> 4) * 128 + (lane & 15) * 8;
}

__device__ __forceinline__ void gload16(const void* g, void* l) {
    __builtin_amdgcn_global_load_lds(
        (const __attribute__((address_space(1))) void*)g,
        (__attribute__((address_space(3))) void*)l, 16, 0, 0);
}

// Split float4 into packed bf16 hi (RNE) and lo (RNE of exact residual).
__device__ __forceinline__ void split4(const float4 v, uint& h01, uint& h23,
                                       uint& l01, uint& l23) {
    const uint u0 = __float_as_uint(v.x) + 0x8000u;
    const uint u1 = __float_as_uint(v.y) + 0x8000u;
    const uint u2 = __float_as_uint(v.z) + 0x8000u;
    const uint u3 = __float_as_uint(v.w) + 0x8000u;
    h01 = __builtin_amdgcn_perm(u1, u0, 0x07060302u);
    h23 = __builtin_amdgcn_perm(u3, u2, 0x07060302u);
    const float f0 = v.x - __uint_as_float(u0 & 0xFFFF0000u);
    const float f1 = v.y - __uint_as_float(u1 & 0xFFFF0000u);
    const float f2 = v.z - __uint_as_float(u2 & 0xFFFF0000u);
    const float f3 = v.w - __uint_as_float(u3 & 0xFFFF0000u);
    l01 = __builtin_amdgcn_perm(__float_as_uint(f1) + 0x8000u,
                                __float_as_uint(f0) + 0x8000u, 0x07060302u);
    l23 = __builtin_amdgcn_perm(__float_as_uint(f3) + 0x8000u,
                                __float_as_uint(f2) + 0x8000u, 0x07060302u);
}

// ---- shared routing decision (validated R5-R15); optionally exports gmask/gtight ----
template <class SC>
__device__ __forceinline__ bool route_core(SC sc, const float* __restrict__ bias,
                                           int* id, float* wv,
                                           unsigned* ogmask = nullptr,
                                           bool* ogtight = nullptr)
{
    float gs[NGROUP];
#pragma unroll
    for (int g = 0; g < NGROUP; ++g) {
        float m1 = -1e30f, m2 = -1e30f;
        for (int i = 0; i < GSIZE; ++i) {
            const int e = g * GSIZE + i;
            const float v = sc(e) + bias[e];
            if (v > m1)      { m2 = m1; m1 = v; }
            else if (v > m2) { m2 = v; }
        }
        gs[g] = m1 + m2;
    }

    unsigned gmask = 0;
    float g4 = -1e30f;
#pragma unroll
    for (int r = 0; r < TOPKG; ++r) {
        int bi = 0; float bv = -1e30f;
#pragma unroll
        for (int g = 0; g < NGROUP; ++g) {
            const bool taken = (gmask >> g) & 1;
            if (!taken && gs[g] > bv) { bv = gs[g]; bi = g; }
        }
        gmask |= 1u << bi;
        g4 = bv;
    }
    float g5 = -1e30f;
#pragma unroll
    for (int g = 0; g < NGROUP; ++g)
        if (!((gmask >> g) & 1) && gs[g] > g5) g5 = gs[g];

    float val[TOPK + 1]; int vid[TOPK + 1];
#pragma unroll
    for (int r = 0; r <= TOPK; ++r) { val[r] = -1e30f; vid[r] = 0; }
    for (int e = 0; e < NEXP; ++e) {
        const bool allowed = (gmask >> (e >> 5)) & 1;
        const float v = allowed ? (sc(e) + bias[e]) : 0.0f;
        if (v > val[TOPK]) {
#pragma unroll
            for (int p = TOPK; p >= 1; --p) {
                if (v > val[p - 1])  { val[p] = val[p - 1]; vid[p] = vid[p - 1]; }
                else if (v > val[p]) { val[p] = v;          vid[p] = e; }
            }
            if (v > val[0]) { val[0] = v; vid[0] = e; }
        }
    }

    const bool gtight = (g4 - g5 < TAUG);
    bool tight = gtight;
#pragma unroll
    for (int i = 0; i < TOPK; ++i) tight |= (val[i] - val[i + 1] < TAU);

    float sum = 0.0f;
#pragma unroll
    for (int r = 0; r < TOPK; ++r) { id[r] = vid[r]; wv[r] = sc(vid[r]); sum += wv[r]; }
    const float inv = RSCALE / (sum + 1e-20f);
#pragma unroll
    for (int r = 0; r < TOPK; ++r) wv[r] *= inv;

    if (ogmask)  *ogmask  = gmask;
    if (ogtight) *ogtight = gtight;
    return tight;
}

// masked top-8 with FIXED gmask over exact sigmoid scores (R15-validated)
__device__ __forceinline__ void masked_top8(const float* __restrict__ lg,
                                            const float* __restrict__ bias,
                                            unsigned gmask, int* id, float* wv)
{
    float val[TOPK]; int vid[TOPK];
#pragma unroll
    for (int r = 0; r < TOPK; ++r) { val[r] = -1e30f; vid[r] = 0; }
    for (int e = 0; e < NEXP; ++e) {
        const bool allowed = (gmask >> (e >> 5)) & 1;
        const float v = allowed ? (lg[e] + bias[e]) : 0.0f;
        if (v > val[TOPK - 1]) {
#pragma unroll
            for (int p = TOPK - 1; p >= 1; --p) {
                if (v > val[p - 1])  { val[p] = val[p - 1]; vid[p] = vid[p - 1]; }
                else if (v > val[p]) { val[p] = v;          vid[p] = e; }
            }
            if (v > val[0]) { val[0] = v; vid[0] = e; }
        }
    }
    float sum = 0.0f;
#pragma unroll
    for (int r = 0; r < TOPK; ++r) { id[r] = vid[r]; wv[r] = lg[vid[r]]; sum += wv[r]; }
    const float inv = RSCALE / (sum + 1e-20f);
#pragma unroll
    for (int r = 0; r < TOPK; ++r) wv[r] *= inv;
}

// exact fp32 recompute + route for one token (cold fallback only)
__device__ void exact_token(const float* __restrict__ hs, const float* __restrict__ wt,
                            const float* __restrict__ bias, float* __restrict__ out, int t)
{
    float lg[NEXP];
    const float* hrow = hs + (size_t)t * HID;
    for (int e = 0; e < NEXP; ++e) {
        const float* wr = wt + (size_t)e * HID;
        float a = 0.0f;
        for (int k = 0; k < HID; k += 4) {
            const float4 x = *(const float4*)(hrow + k);
            const float4 b = *(const float4*)(wr + k);
            a = fmaf(x.x, b.x, a); a = fmaf(x.y, b.y, a);
            a = fmaf(x.z, b.z, a); a = fmaf(x.w, b.w, a);
        }
        lg[e] = 1.0f / (1.0f + expf(-a));
    }
    int id[TOPK]; float wv[TOPK];
    route_core([&](int e) { return lg[e]; }, bias, id, wv);
    for (int r = 0; r < TOPK; ++r) {
        out[(size_t)t * TOPK + r] = (float)id[r];
        out[(size_t)T_TOKENS * TOPK + (size_t)t * TOPK + r] = wv[r];
    }
}

// =============== one-shot weight conversion v2: coalesced writes ===============
// thread g -> (sg, e_hi, kch, e_lo) with e_lo fastest => per-wave 1KB contiguous
// stores per limb. Same wq layout as R9: idx = sg*8192 + (e>>4)*512 + kch*128 + (e&15)*8
__global__ __launch_bounds__(256, 8)
void conv_weight(const float* __restrict__ wt, ushort* __restrict__ wq)
{
    const int g    = blockIdx.x * 256 + threadIdx.x;   // 131072 threads
    const int e_lo = g & 15;
    const int kch  = (g >> 4) & 3;
    const int e_hi = (g >> 6) & 15;
    const int sg   = g >> 10;                          // 0..127
    const int e    = e_hi * 16 + e_lo;
    const int k0   = sg * 32 + kch * 8;

    const float4 v0 = *(const float4*)(wt + (size_t)e * HID + k0);
    const float4 v1 = *(const float4*)(wt + (size_t)e * HID + k0 + 4);
    uint h01, h23, l01, l23, h45, h67, l45, l67;
    split4(v0, h01, h23, l01, l23);
    split4(v1, h45, h67, l45, l67);

    const size_t idx = (size_t)sg * 8192 + (size_t)(e_hi * 512 + kch * 128 + e_lo * 8);
    uint4 hv; hv.x = h01; hv.y = h23; hv.z = h45; hv.w = h67;
    uint4 lv; lv.x = l01; lv.y = l23; lv.z = l45; lv.w = l67;
    *(uint4*)&wq[idx] = hv;
    *(uint4*)&wq[(size_t)WQ_LIMB + idx] = lv;
}

// =============== split-K GEMM v2 (R14-verbatim: R9 loop + XCD-local swizzle) ===============
__global__ __launch_bounds__(256, 4)
void router_gemm(const float* __restrict__ hs, const ushort* __restrict__ wq,
                 float* __restrict__ pw)
{
    __shared__ ushort u16[STG_TOT];

    const int tid  = threadIdx.x;
    const int lane = tid & 63;
    const int w    = tid >> 6;
    const int b    = blockIdx.x;
    const int m    = (b >> 5) * 8 + (b & 7);
    const int sk   = (b >> 3) & 3;
    const int t0   = m * BM;
    const int kb0  = sk * KSPAN;
    const int r0   = tid >> 3;
    const int q    = tid & 7;

    const ushort* wq_hi = wq;
    const ushort* wq_lo = wq + WQ_LIMB;

    f32x4 acc[4][4];
#pragma unroll
    for (int i = 0; i < 4; ++i)
#pragma unroll
        for (int j = 0; j < 4; ++j) acc[i][j] = (f32x4)0.0f;

    float4 ra[2];
#pragma unroll
    for (int s = 0; s < 2; ++s)
        ra[s] = *(const float4*)(hs + (size_t)(t0 + r0 + 32 * s) * HID + kb0 + q * 4);

    for (int ks = 0; ks < NKS; ++ks) {
        const int sg = sk * NKS + ks;
        __syncthreads();

        {
            const size_t gb = (size_t)sg * 8192 + (size_t)(w * 4) * 512 + (size_t)lane * 8;
#pragma unroll
            for (int i = 0; i < 4; ++i) {
                gload16(wq_hi + gb + i * 512, &u16[B_HI + (w * 4 + i) * 512]);
                gload16(wq_lo + gb + i * 512, &u16[B_LO + (w * 4 + i) * 512]);
            }
        }
#pragma unroll
        for (int s = 0; s < 2; ++s) {
            const int r = r0 + 32 * s;
            uint h01, h23, l01, l23;
            split4(ra[s], h01, h23, l01, l23);
            const int eo = stoffA(r, q);
            uint2 hv; hv.x = h01; hv.y = h23;
            uint2 lv; lv.x = l01; lv.y = l23;
            *(uint2*)&u16[A_HI + eo] = hv;
            *(uint2*)&u16[A_LO + eo] = lv;
        }
        __syncthreads();

        if (ks + 1 < NKS) {
            const int kb = kb0 + (ks + 1) * BK;
#pragma unroll
            for (int s = 0; s < 2; ++s)
                ra[s] = *(const float4*)(hs + (size_t)(t0 + r0 + 32 * s) * HID + kb + q * 4);
        }

        const int fo = froffL(lane);
        bf16x8 ah[4], al[4];
#pragma unroll
        for (int rt = 0; rt < 4; ++rt) {
            ah[rt] = *(const bf16x8*)&u16[A_HI + rt * 512 + fo];
            al[rt] = *(const bf16x8*)&u16[A_LO + rt * 512 + fo];
        }
#pragma unroll
        for (int c = 0; c < 4; ++c) {
            const int ct = w * 4 + c;
            const bf16x8 bh = *(const bf16x8*)&u16[B_HI + ct * 512 + fo];
            const bf16x8 bl = *(const bf16x8*)&u16[B_LO + ct * 512 + fo];
#pragma unroll
            for (int rt = 0; rt < 4; ++rt) {
                acc[rt][c] = __builtin_amdgcn_mfma_f32_16x16x32_bf16(ah[rt], bh, acc[rt][c], 0, 0, 0);
                acc[rt][c] = __builtin_amdgcn_mfma_f32_16x16x32_bf16(ah[rt], bl, acc[rt][c], 0, 0, 0);
                acc[rt][c] = __builtin_amdgcn_mfma_f32_16x16x32_bf16(al[rt], bh, acc[rt][c], 0, 0, 0);
            }
        }
    }

#pragma unroll
    for (int rt = 0; rt < 4; ++rt)
#pragma unroll
        for (int c = 0; c < 4; ++c) {
            const int col  = w * 64 + c * 16 + (lane & 15);
            const int rowb = rt * 16 + (lane >> 4) * 4;
#pragma unroll
            for (int j = 0; j < 4; ++j)
                pw[((size_t)(sk * T_TOKENS) + t0 + rowb + j) * NEXP + col] = acc[rt][c][j];
        }
}

// =============== routing v3: vectorized pw reads (wave=4 tokens, lane=4 experts) ===============
__global__ __launch_bounds__(256, 4)
void router_route(const float* __restrict__ pw, const float* __restrict__ bias,
                  float* __restrict__ out,
                  unsigned* __restrict__ wcnt, unsigned* __restrict__ wlist,
                  unsigned cap)
{
    __shared__ float Lg[RT_TOK * RT_STR];  // 16.25 KB, row-major [token][expert]
    const int tid  = threadIdx.x;
    const int b    = blockIdx.x;
    const int x    = b & 7;
    const int rest = b >> 3;
    const int m    = (rest >> 2) * 8 + x;   // XCD-matched (R14)
    const int sub  = rest & 3;
    const int t0   = m * BM + sub * RT_TOK;

    const int wv = tid >> 6;               // wave -> 4 tokens
    const int l  = tid & 63;               // lane -> 4 experts

#pragma unroll
    for (int j = 0; j < 4; ++j) {
        const int tt = wv * 4 + j;
        const int t  = t0 + tt;
        float4 a = {0.0f, 0.0f, 0.0f, 0.0f};
#pragma unroll
        for (int s = 0; s < SPLITK; ++s) {  // FIXED order (deterministic)
            const float4 v = *(const float4*)&pw[((size_t)(s * T_TOKENS) + t) * NEXP + l * 4];
            a.x += v.x; a.y += v.y; a.z += v.z; a.w += v.w;
        }
        float4 r;
        r.x = 1.0f / (1.0f + expf(-a.x));
        r.y = 1.0f / (1.0f + expf(-a.y));
        r.z = 1.0f / (1.0f + expf(-a.z));
        r.w = 1.0f / (1.0f + expf(-a.w));
        *(float4*)&Lg[tt * RT_STR + l * 4] = r;
    }
    __syncthreads();

    if (tid < RT_TOK) {
        const int t = t0 + tid;
        int id[TOPK]; float wv2[TOPK];
        unsigned gm; bool gt;
        const bool tight = route_core(
            [&](int e) { return Lg[tid * RT_STR + e]; }, bias, id, wv2, &gm, &gt);

#pragma unroll
        for (int r = 0; r < TOPK; ++r) {
            out[(size_t)t * TOPK + r] = (float)id[r];
            out[(size_t)T_TOKENS * TOPK + (size_t)t * TOPK + r] = wv2[r];
        }
        if (tight) {
            const unsigned pos = atomicAdd(wcnt, 1u);
            if (pos < cap)
                wlist[pos] = (unsigned)t | (gm << 16) | (gt ? (1u << 30) : 0u);
        }
    }
}

// 4-expert exact dot, 2-deep pipelined loads (>=8 in flight), butterfly reduce
__device__ __forceinline__ void dot4(const float* __restrict__ hrow,
                                     const float* __restrict__ wt,
                                     float* __restrict__ lg, int e0, int lane)
{
    float a[4] = {0.0f, 0.0f, 0.0f, 0.0f};
    const float* wp[4];
#pragma unroll
    for (int p = 0; p < 4; ++p) wp[p] = wt + (size_t)(e0 + p) * HID;

    float4 vb[4], vn[4];
#pragma unroll
    for (int p = 0; p < 4; ++p) vb[p] = *(const float4*)(wp[p] + lane * 4);

#pragma unroll
    for (int j = 0; j < 16; ++j) {
        if (j < 15) {
            const int f4n = (j + 1) * 64 + lane;
#pragma unroll
            for (int p = 0; p < 4; ++p) vn[p] = *(const float4*)(wp[p] + f4n * 4);
        }
        const float4 h = *(const float4*)&hrow[(j * 64 + lane) * 4];
#pragma unroll
        for (int p = 0; p < 4; ++p) {
            a[p] = fmaf(h.x, vb[p].x, a[p]); a[p] = fmaf(h.y, vb[p].y, a[p]);
            a[p] = fmaf(h.z, vb[p].z, a[p]); a[p] = fmaf(h.w, vb[p].w, a[p]);
        }
#pragma unroll
        for (int p = 0; p < 4; ++p) vb[p] = vn[p];
    }
#pragma unroll
    for (int p = 0; p < 4; ++p)
#pragma unroll
        for (int d = 1; d < 64; d <<= 1)
            a[p] += __shfl_xor(a[p], d, 64);
    if (lane == 0) {
#pragma unroll
        for (int p = 0; p < 4; ++p)
            lg[e0 + p] = 1.0f / (1.0f + expf(-a[p]));
    }
}

// =============== cleanup v8: v6 control flow + pipelined dot4 ===============
__global__ __launch_bounds__(256, 4)
void router_exact(const float* __restrict__ hs, const float* __restrict__ wt,
                  const float* __restrict__ bias, float* __restrict__ out,
                  const unsigned* __restrict__ wcnt, const unsigned* __restrict__ wlist,
                  unsigned cap)
{
    __shared__ float hrow[HID];          // 16 KB
    __shared__ float lg[NEXP];           // 1 KB
    __shared__ int   sh_grp[4];
    __shared__ int   sh_full;
    const unsigned count = min(*wcnt, cap);
    const int tid  = threadIdx.x;
    const int lane = tid & 63;
    const int w    = tid >> 6;

    for (unsigned b = blockIdx.x; b < count; b += gridDim.x) {
        __syncthreads();                 // guard reuse across passes
        const unsigned ent = wlist[b];
        const int t          = (int)(ent & 0xFFFFu);
        const unsigned gmask = (ent >> 16) & 0xFFu;
        const bool gtight    = (ent >> 30) & 1u;

        if (tid < 4) {                   // tid-th set bit of gmask (exactly 4 set)
            unsigned mm = gmask; int g = 0;
            for (int i = 0; i <= tid; ++i) { g = __ffs(mm) - 1; mm &= mm - 1; }
            sh_grp[tid] = g;
        }
        if (tid == 0) sh_full = gtight ? 1 : 0;

#pragma unroll
        for (int i = 0; i < 4; ++i) {
            const int f4 = i * 256 + tid;
            *(float4*)&hrow[f4 * 4] = *(const float4*)(hs + (size_t)t * HID + f4 * 4);
        }
        __syncthreads();

        bool full = (sh_full != 0);
        if (!full) {
            const int eb = sh_grp[w] * GSIZE;
            for (int g2 = 0; g2 < 8; ++g2)
                dot4(hrow, wt, lg, eb + g2 * 4, lane);
            __syncthreads();
            if (tid == 0) {
                int pos = 0;
                for (int e = 0; e < NEXP; ++e)
                    if (((gmask >> (e >> 5)) & 1) && lg[e] + bias[e] > 0.0f) ++pos;
                sh_full = (pos < TOPK) ? 1 : 0;
            }
            __syncthreads();
            full = (sh_full != 0);
        }
        if (full) {
            for (int g = 0; g < 16; ++g)
                dot4(hrow, wt, lg, w * 64 + g * 4, lane);
            __syncthreads();
        }

        if (tid == 0) {
            int id[TOPK]; float wv[TOPK];
            if (full)
                route_core([&](int e) { return lg[e]; }, bias, id, wv);
            else
                masked_top8(lg, bias, gmask, id, wv);
            for (int r = 0; r < TOPK; ++r) {
                out[(size_t)t * TOPK + r] = (float)id[r];
                out[(size_t)T_TOKENS * TOPK + (size_t)t * TOPK + r] = wv[r];
            }
        }
    }
}

// =============== fallback monolith (R5-validated; packs wlist) ===============
__global__ __launch_bounds__(512, 1)
void router_mono(const float* __restrict__ hs, const float* __restrict__ wt,
                 const float* __restrict__ bias, float* __restrict__ out,
                 unsigned* __restrict__ wcnt, unsigned* __restrict__ wlist, unsigned cap)
{
    __shared__ float smem[16384];
    ushort* u16 = (ushort*)smem;
    float*  Lg  = smem;

    const int tid  = threadIdx.x;
    const int lane = tid & 63;
    const int w    = tid >> 6;
    const int t0   = blockIdx.x * 64;
    const int ar   = tid >> 3;
    const int aq   = tid & 7;

    f32x4 acc[4][2];
#pragma unroll
    for (int i = 0; i < 4; ++i)
#pragma unroll
        for (int j = 0; j < 2; ++j) acc[i][j] = (f32x4)0.0f;

    float4 ra, rb[4];
    ra = *(const float4*)(hs + (size_t)(t0 + ar) * HID + aq * 4);
#pragma unroll
    for (int s = 0; s < 4; ++s)
        rb[s] = *(const float4*)(wt + (size_t)(ar + s * 64) * HID + aq * 4);

    for (int ks = 0; ks < HID / BK; ++ks) {
        __syncthreads();
        {
            uint h01, h23, l01, l23;
            split4(ra, h01, h23, l01, l23);
            const int eo = stoffA(ar, aq);
            uint2 hv; hv.x = h01; hv.y = h23;
            uint2 lv; lv.x = l01; lv.y = l23;
            *(uint2*)&u16[0 + eo] = hv;
            *(uint2*)&u16[2048 + eo] = lv;
        }
#pragma unroll
        for (int s = 0; s < 4; ++s) {
            const int e = ar + s * 64;
            uint h01, h23, l01, l23;
            split4(rb[s], h01, h23, l01, l23);
            const int eo = stoffA(e, aq);
            uint2 hv; hv.x = h01; hv.y = h23;
            uint2 lv; lv.x = l01; lv.y = l23;
            *(uint2*)&u16[4096 + eo] = hv;
            *(uint2*)&u16[12288 + eo] = lv;
        }
        __syncthreads();
        if (ks + 1 < HID / BK) {
            const int k0 = (ks + 1) * BK;
            ra = *(const float4*)(hs + (size_t)(t0 + ar) * HID + k0 + aq * 4);
#pragma unroll
            for (int s = 0; s < 4; ++s)
                rb[s] = *(const float4*)(wt + (size_t)(ar + s * 64) * HID + k0 + aq * 4);
        }
        const int fo = froffL(lane);
        bf16x8 ah[4], al[4];
#pragma unroll
        for (int rt = 0; rt < 4; ++rt) {
            ah[rt] = *(const bf16x8*)&u16[0 + rt * 512 + fo];
            al[rt] = *(const bf16x8*)&u16[2048 + rt * 512 + fo];
        }
#pragma unroll
        for (int c = 0; c < 2; ++c) {
            const int ct = w * 2 + c;
            const bf16x8 bh = *(const bf16x8*)&u16[4096 + ct * 512 + fo];
            const bf16x8 bl = *(const bf16x8*)&u16[12288 + ct * 512 + fo];
#pragma unroll
            for (int rt = 0; rt < 4; ++rt) {
                acc[rt][c] = __builtin_amdgcn_mfma_f32_16x16x32_bf16(ah[rt], bh, acc[rt][c], 0, 0, 0);
                acc[rt][c] = __builtin_amdgcn_mfma_f32_16x16x32_bf16(ah[rt], bl, acc[rt][c], 0, 0, 0);
                acc[rt][c] = __builtin_amdgcn_mfma_f32_16x16x32_bf16(al[rt], bh, acc[rt][c], 0, 0, 0);
            }
        }
    }
    __syncthreads();
#pragma unroll
    for (int rt = 0; rt < 4; ++rt)
#pragma unroll
        for (int c = 0; c < 2; ++c) {
            const int col  = w * 32 + c * 16 + (lane & 15);
            const int rowb = rt * 16 + (lane >> 4) * 4;
#pragma unroll
            for (int j = 0; j < 4; ++j) {
                const int row = rowb + j;
                Lg[col * 64 + ((row + col) & 63)] = 1.0f / (1.0f + expf(-acc[rt][c][j]));
            }
        }
    __syncthreads();

    if (tid < 64) {
        const int t = t0 + tid;
        int id[TOPK]; float wv[TOPK];
        unsigned gm; bool gt;
        const bool tight = route_core(
            [&](int e) { return Lg[e * 64 + ((tid + e) & 63)]; }, bias, id, wv, &gm, &gt);
#pragma unroll
        for (int r = 0; r < TOPK; ++r) {
            out[(size_t)t * TOPK + r] = (float)id[r];
            out[(size_t)T_TOKENS * TOPK + (size_t)t * TOPK + r] = wv[r];
        }
        if (tight) {
            bool queued = false;
            if (wcnt) {
                const unsigned pos = atomicAdd(wcnt, 1u);
                if (pos < cap) {
                    wlist[pos] = (unsigned)t | (gm << 16) | (gt ? (1u << 30) : 0u);
                    queued = true;
                }
            }
            if (!queued) exact_token(hs, wt, bias, out, t);
        }
    }
}

extern "C" void kernel_launch(void* const* d_in, const int* in_sizes, int n_in,
                              void* d_out, int out_size, void* d_ws, size_t ws_size,
                              hipStream_t stream) {
    const float* hs   = (const float*)d_in[0];   // [16384, 4096] f32
    const float* wt   = (const float*)d_in[1];   // [256, 4096]   f32
    const float* bias = (const float*)d_in[2];   // [256]         f32
    float* out = (float*)d_out;
    (void)in_sizes; (void)n_in; (void)out_size;

    const size_t PW_BYTES = (size_t)SPLITK * T_TOKENS * NEXP * 4;   // 64 MB
    const size_t WQ_BYTES = (size_t)2 * WQ_LIMB * 2;                // 4 MB
    const size_t NEED = PW_BYTES + WQ_BYTES + 4 + (size_t)T_TOKENS * 4;

    if (ws_size >= NEED) {
        float*    pw    = (float*)d_ws;
        ushort*   wq    = (ushort*)((char*)d_ws + PW_BYTES);
        unsigned* wcnt  = (unsigned*)((char*)d_ws + PW_BYTES + WQ_BYTES);
        unsigned* wlist = wcnt + 1;
        hipMemsetAsync(wcnt, 0, sizeof(unsigned), stream);
        conv_weight<<<512, 256, 0, stream>>>(wt, wq);
        router_gemm<<<(T_TOKENS / BM) * SPLITK, 256, 0, stream>>>(hs, wq, pw);
        router_route<<<T_TOKENS / RT_TOK, 256, 0, stream>>>(pw, bias, out, wcnt, wlist,
                                                            (unsigned)T_TOKENS);
        router_exact<<<2048, 256, 0, stream>>>(hs, wt, bias, out, wcnt, wlist,
                                               (unsigned)T_TOKENS);
    } else if (ws_size >= 8) {
        unsigned cap = (unsigned)((ws_size - 4) / 4);
        if (cap > T_TOKENS) cap = T_TOKENS;
        unsigned* wcnt  = (unsigned*)d_ws;
        unsigned* wlist = wcnt + 1;
        hipMemsetAsync(d_ws, 0, sizeof(unsigned), stream);
        router_mono<<<T_TOKENS / 64, 512, 0, stream>>>(hs, wt, bias, out, wcnt, wlist, cap);
        router_exact<<<2048, 256, 0, stream>>>(hs, wt, bias, out, wcnt, wlist, cap);
    } else {
        router_mono<<<T_TOKENS / 64, 512, 0, stream>>>(hs, wt, bias, out,
                                                       nullptr, nullptr, 0u);
    }
}

// Round 17
// 467.209 us; speedup vs baseline: 1.0360x; 1.0360x over previous
//
#include <hip/hip_runtime.h>
#include <math.h>

#define T_TOKENS 16384
#define HID      4096
#define NEXP     256
#define NGROUP   8
#define GSIZE    32
#define TOPKG    4
#define TOPK     8
#define RSCALE   2.5f

#define TAU   1.5e-5f    // expert-score margin (R13-R16-validated, 9 sigma)
#define TAUG  2.5e-5f    // group-score margin

// ---- split-K GEMM config (R9/R14-validated) ----
#define BM     64
#define BK     32
#define SPLITK 4
#define KSPAN  (HID / SPLITK)    // 1024
#define NKS    (KSPAN / BK)      // 32 K-steps per block
#define NSG    (HID / BK)        // 128 global K-steps

// LDS staging (ushort units), UNPADDED frag-major (R9-validated)
#define A_HI   0
#define A_LO   2048
#define B_HI   4096
#define B_LO   12288
#define STG_TOT 20480            // 40 KB -> 4 blocks/CU

#define WQ_LIMB (NSG * 8192)
#define RT_TOK 16                // route tokens/block (R14-validated)
#define RT_STR 260               // Lg row stride (16B-aligned)

typedef __attribute__((ext_vector_type(8))) short bf16x8;
typedef __attribute__((ext_vector_type(4))) float f32x4;

__device__ __forceinline__ int stoffA(int r, int q) {
    return (r >> 4) * 512 + (q >> 1) * 128 + (r & 15) * 8 + (q & 1) * 4;
}
__device__ __forceinline__ int froffL(int lane) {
    return (lane >> 4) * 128 + (lane & 15) * 8;
}

__device__ __forceinline__ void gload16(const void* g, void* l) {
    __builtin_amdgcn_global_load_lds(
        (const __attribute__((address_space(1))) void*)g,
        (__attribute__((address_space(3))) void*)l, 16, 0, 0);
}

// Split float4 into packed bf16 hi (RNE) and lo (RNE of exact residual).
__device__ __forceinline__ void split4(const float4 v, uint& h01, uint& h23,
                                       uint& l01, uint& l23) {
    const uint u0 = __float_as_uint(v.x) + 0x8000u;
    const uint u1 = __float_as_uint(v.y) + 0x8000u;
    const uint u2 = __float_as_uint(v.z) + 0x8000u;
    const uint u3 = __float_as_uint(v.w) + 0x8000u;
    h01 = __builtin_amdgcn_perm(u1, u0, 0x07060302u);
    h23 = __builtin_amdgcn_perm(u3, u2, 0x07060302u);
    const float f0 = v.x - __uint_as_float(u0 & 0xFFFF0000u);
    const float f1 = v.y - __uint_as_float(u1 & 0xFFFF0000u);
    const float f2 = v.z - __uint_as_float(u2 & 0xFFFF0000u);
    const float f3 = v.w - __uint_as_float(u3 & 0xFFFF0000u);
    l01 = __builtin_amdgcn_perm(__float_as_uint(f1) + 0x8000u,
                                __float_as_uint(f0) + 0x8000u, 0x07060302u);
    l23 = __builtin_amdgcn_perm(__float_as_uint(f3) + 0x8000u,
                                __float_as_uint(f2) + 0x8000u, 0x07060302u);
}

// ---- shared routing decision (validated R5-R16); exports gmask/gtight ----
template <class SC>
__device__ __forceinline__ bool route_core(SC sc, const float* __restrict__ bias,
                                           int* id, float* wv,
                                           unsigned* ogmask = nullptr,
                                           bool* ogtight = nullptr)
{
    float gs[NGROUP];
#pragma unroll
    for (int g = 0; g < NGROUP; ++g) {
        float m1 = -1e30f, m2 = -1e30f;
        for (int i = 0; i < GSIZE; ++i) {
            const int e = g * GSIZE + i;
            const float v = sc(e) + bias[e];
            if (v > m1)      { m2 = m1; m1 = v; }
            else if (v > m2) { m2 = v; }
        }
        gs[g] = m1 + m2;
    }

    unsigned gmask = 0;
    float g4 = -1e30f;
#pragma unroll
    for (int r = 0; r < TOPKG; ++r) {
        int bi = 0; float bv = -1e30f;
#pragma unroll
        for (int g = 0; g < NGROUP; ++g) {
            const bool taken = (gmask >> g) & 1;
            if (!taken && gs[g] > bv) { bv = gs[g]; bi = g; }
        }
        gmask |= 1u << bi;
        g4 = bv;
    }
    float g5 = -1e30f;
#pragma unroll
    for (int g = 0; g < NGROUP; ++g)
        if (!((gmask >> g) & 1) && gs[g] > g5) g5 = gs[g];

    float val[TOPK + 1]; int vid[TOPK + 1];
#pragma unroll
    for (int r = 0; r <= TOPK; ++r) { val[r] = -1e30f; vid[r] = 0; }
    for (int e = 0; e < NEXP; ++e) {
        const bool allowed = (gmask >> (e >> 5)) & 1;
        const float v = allowed ? (sc(e) + bias[e]) : 0.0f;
        if (v > val[TOPK]) {
#pragma unroll
            for (int p = TOPK; p >= 1; --p) {
                if (v > val[p - 1])  { val[p] = val[p - 1]; vid[p] = vid[p - 1]; }
                else if (v > val[p]) { val[p] = v;          vid[p] = e; }
            }
            if (v > val[0]) { val[0] = v; vid[0] = e; }
        }
    }

    const bool gtight = (g4 - g5 < TAUG);
    bool tight = gtight;
#pragma unroll
    for (int i = 0; i < TOPK; ++i) tight |= (val[i] - val[i + 1] < TAU);

    float sum = 0.0f;
#pragma unroll
    for (int r = 0; r < TOPK; ++r) { id[r] = vid[r]; wv[r] = sc(vid[r]); sum += wv[r]; }
    const float inv = RSCALE / (sum + 1e-20f);
#pragma unroll
    for (int r = 0; r < TOPK; ++r) wv[r] *= inv;

    if (ogmask)  *ogmask  = gmask;
    if (ogtight) *ogtight = gtight;
    return tight;
}

// masked top-8 with FIXED gmask over exact sigmoid scores (R15-validated)
__device__ __forceinline__ void masked_top8(const float* __restrict__ lg,
                                            const float* __restrict__ bias,
                                            unsigned gmask, int* id, float* wv)
{
    float val[TOPK]; int vid[TOPK];
#pragma unroll
    for (int r = 0; r < TOPK; ++r) { val[r] = -1e30f; vid[r] = 0; }
    for (int e = 0; e < NEXP; ++e) {
        const bool allowed = (gmask >> (e >> 5)) & 1;
        const float v = allowed ? (lg[e] + bias[e]) : 0.0f;
        if (v > val[TOPK - 1]) {
#pragma unroll
            for (int p = TOPK - 1; p >= 1; --p) {
                if (v > val[p - 1])  { val[p] = val[p - 1]; vid[p] = vid[p - 1]; }
                else if (v > val[p]) { val[p] = v;          vid[p] = e; }
            }
            if (v > val[0]) { val[0] = v; vid[0] = e; }
        }
    }
    float sum = 0.0f;
#pragma unroll
    for (int r = 0; r < TOPK; ++r) { id[r] = vid[r]; wv[r] = lg[vid[r]]; sum += wv[r]; }
    const float inv = RSCALE / (sum + 1e-20f);
#pragma unroll
    for (int r = 0; r < TOPK; ++r) wv[r] *= inv;
}

// exact fp32 recompute + route for one token (cold fallback only)
__device__ void exact_token(const float* __restrict__ hs, const float* __restrict__ wt,
                            const float* __restrict__ bias, float* __restrict__ out, int t)
{
    float lg[NEXP];
    const float* hrow = hs + (size_t)t * HID;
    for (int e = 0; e < NEXP; ++e) {
        const float* wr = wt + (size_t)e * HID;
        float a = 0.0f;
        for (int k = 0; k < HID; k += 4) {
            const float4 x = *(const float4*)(hrow + k);
            const float4 b = *(const float4*)(wr + k);
            a = fmaf(x.x, b.x, a); a = fmaf(x.y, b.y, a);
            a = fmaf(x.z, b.z, a); a = fmaf(x.w, b.w, a);
        }
        lg[e] = 1.0f / (1.0f + expf(-a));
    }
    int id[TOPK]; float wv[TOPK];
    route_core([&](int e) { return lg[e]; }, bias, id, wv);
    for (int r = 0; r < TOPK; ++r) {
        out[(size_t)t * TOPK + r] = (float)id[r];
        out[(size_t)T_TOKENS * TOPK + (size_t)t * TOPK + r] = wv[r];
    }
}

// 4-expert exact dot (R15-validated simple form — compiler batches loads)
__device__ __forceinline__ void dot4(const float* __restrict__ hrow,
                                     const float* __restrict__ wt,
                                     float* __restrict__ lg, int e0, int lane)
{
    float a[4] = {0.0f, 0.0f, 0.0f, 0.0f};
#pragma unroll 4
    for (int j = 0; j < 16; ++j) {
        const int f4 = j * 64 + lane;
        const float4 h = *(const float4*)&hrow[f4 * 4];
#pragma unroll
        for (int p = 0; p < 4; ++p) {
            const float4 v = *(const float4*)(wt + (size_t)(e0 + p) * HID + f4 * 4);
            a[p] = fmaf(h.x, v.x, a[p]); a[p] = fmaf(h.y, v.y, a[p]);
            a[p] = fmaf(h.z, v.z, a[p]); a[p] = fmaf(h.w, v.w, a[p]);
        }
    }
#pragma unroll
    for (int p = 0; p < 4; ++p)
#pragma unroll
        for (int d = 1; d < 64; d <<= 1)
            a[p] += __shfl_xor(a[p], d, 64);
    if (lane == 0) {
#pragma unroll
        for (int p = 0; p < 4; ++p)
            lg[e0 + p] = 1.0f / (1.0f + expf(-a[p]));
    }
}

// =============== one-shot weight conversion v2 (R16, coalesced writes) ===============
__global__ __launch_bounds__(256, 8)
void conv_weight(const float* __restrict__ wt, ushort* __restrict__ wq)
{
    const int g    = blockIdx.x * 256 + threadIdx.x;   // 131072 threads
    const int e_lo = g & 15;
    const int kch  = (g >> 4) & 3;
    const int e_hi = (g >> 6) & 15;
    const int sg   = g >> 10;                          // 0..127
    const int e    = e_hi * 16 + e_lo;
    const int k0   = sg * 32 + kch * 8;

    const float4 v0 = *(const float4*)(wt + (size_t)e * HID + k0);
    const float4 v1 = *(const float4*)(wt + (size_t)e * HID + k0 + 4);
    uint h01, h23, l01, l23, h45, h67, l45, l67;
    split4(v0, h01, h23, l01, l23);
    split4(v1, h45, h67, l45, l67);

    const size_t idx = (size_t)sg * 8192 + (size_t)(e_hi * 512 + kch * 128 + e_lo * 8);
    uint4 hv; hv.x = h01; hv.y = h23; hv.z = h45; hv.w = h67;
    uint4 lv; lv.x = l01; lv.y = l23; lv.z = l45; lv.w = l67;
    *(uint4*)&wq[idx] = hv;
    *(uint4*)&wq[(size_t)WQ_LIMB + idx] = lv;
}

// =============== split-K GEMM v2 (R14-verbatim) ===============
__global__ __launch_bounds__(256, 4)
void router_gemm(const float* __restrict__ hs, const ushort* __restrict__ wq,
                 float* __restrict__ pw)
{
    __shared__ ushort u16[STG_TOT];

    const int tid  = threadIdx.x;
    const int lane = tid & 63;
    const int w    = tid >> 6;
    const int b    = blockIdx.x;
    const int m    = (b >> 5) * 8 + (b & 7);
    const int sk   = (b >> 3) & 3;
    const int t0   = m * BM;
    const int kb0  = sk * KSPAN;
    const int r0   = tid >> 3;
    const int q    = tid & 7;

    const ushort* wq_hi = wq;
    const ushort* wq_lo = wq + WQ_LIMB;

    f32x4 acc[4][4];
#pragma unroll
    for (int i = 0; i < 4; ++i)
#pragma unroll
        for (int j = 0; j < 4; ++j) acc[i][j] = (f32x4)0.0f;

    float4 ra[2];
#pragma unroll
    for (int s = 0; s < 2; ++s)
        ra[s] = *(const float4*)(hs + (size_t)(t0 + r0 + 32 * s) * HID + kb0 + q * 4);

    for (int ks = 0; ks < NKS; ++ks) {
        const int sg = sk * NKS + ks;
        __syncthreads();

        {
            const size_t gb = (size_t)sg * 8192 + (size_t)(w * 4) * 512 + (size_t)lane * 8;
#pragma unroll
            for (int i = 0; i < 4; ++i) {
                gload16(wq_hi + gb + i * 512, &u16[B_HI + (w * 4 + i) * 512]);
                gload16(wq_lo + gb + i * 512, &u16[B_LO + (w * 4 + i) * 512]);
            }
        }
#pragma unroll
        for (int s = 0; s < 2; ++s) {
            const int r = r0 + 32 * s;
            uint h01, h23, l01, l23;
            split4(ra[s], h01, h23, l01, l23);
            const int eo = stoffA(r, q);
            uint2 hv; hv.x = h01; hv.y = h23;
            uint2 lv; lv.x = l01; lv.y = l23;
            *(uint2*)&u16[A_HI + eo] = hv;
            *(uint2*)&u16[A_LO + eo] = lv;
        }
        __syncthreads();

        if (ks + 1 < NKS) {
            const int kb = kb0 + (ks + 1) * BK;
#pragma unroll
            for (int s = 0; s < 2; ++s)
                ra[s] = *(const float4*)(hs + (size_t)(t0 + r0 + 32 * s) * HID + kb + q * 4);
        }

        const int fo = froffL(lane);
        bf16x8 ah[4], al[4];
#pragma unroll
        for (int rt = 0; rt < 4; ++rt) {
            ah[rt] = *(const bf16x8*)&u16[A_HI + rt * 512 + fo];
            al[rt] = *(const bf16x8*)&u16[A_LO + rt * 512 + fo];
        }
#pragma unroll
        for (int c = 0; c < 4; ++c) {
            const int ct = w * 4 + c;
            const bf16x8 bh = *(const bf16x8*)&u16[B_HI + ct * 512 + fo];
            const bf16x8 bl = *(const bf16x8*)&u16[B_LO + ct * 512 + fo];
#pragma unroll
            for (int rt = 0; rt < 4; ++rt) {
                acc[rt][c] = __builtin_amdgcn_mfma_f32_16x16x32_bf16(ah[rt], bh, acc[rt][c], 0, 0, 0);
                acc[rt][c] = __builtin_amdgcn_mfma_f32_16x16x32_bf16(ah[rt], bl, acc[rt][c], 0, 0, 0);
                acc[rt][c] = __builtin_amdgcn_mfma_f32_16x16x32_bf16(al[rt], bh, acc[rt][c], 0, 0, 0);
            }
        }
    }

#pragma unroll
    for (int rt = 0; rt < 4; ++rt)
#pragma unroll
        for (int c = 0; c < 4; ++c) {
            const int col  = w * 64 + c * 16 + (lane & 15);
            const int rowb = rt * 16 + (lane >> 4) * 4;
#pragma unroll
            for (int j = 0; j < 4; ++j)
                pw[((size_t)(sk * T_TOKENS) + t0 + rowb + j) * NEXP + col] = acc[rt][c][j];
        }
}

// =============== routing v4: v3 fast path + INLINE exact cleanup ===============
__global__ __launch_bounds__(256, 4)
void router_route(const float* __restrict__ pw, const float* __restrict__ hs,
                  const float* __restrict__ wt, const float* __restrict__ bias,
                  float* __restrict__ out)
{
    __shared__ float    Lg[RT_TOK * RT_STR];   // 16640 B
    __shared__ float    hrow[HID];             // 16384 B
    __shared__ float    lg[NEXP];              // 1024 B
    __shared__ int      sh_grp[4];
    __shared__ unsigned sh_tight[RT_TOK];      // 0 = clean; else gmask<<16|gtight<<30|1

    const int tid  = threadIdx.x;
    const int lane = tid & 63;
    const int w    = tid >> 6;
    const int b    = blockIdx.x;
    const int x    = b & 7;
    const int rest = b >> 3;
    const int m    = (rest >> 2) * 8 + x;       // XCD-matched (R14)
    const int sub  = rest & 3;
    const int t0   = m * BM + sub * RT_TOK;

    // ---- fast path: vectorized pw sum -> sigmoid -> Lg (R16 v3) ----
#pragma unroll
    for (int j = 0; j < 4; ++j) {
        const int tt = w * 4 + j;
        const int t  = t0 + tt;
        float4 a = {0.0f, 0.0f, 0.0f, 0.0f};
#pragma unroll
        for (int s = 0; s < SPLITK; ++s) {      // FIXED order (deterministic)
            const float4 v = *(const float4*)&pw[((size_t)(s * T_TOKENS) + t) * NEXP + lane * 4];
            a.x += v.x; a.y += v.y; a.z += v.z; a.w += v.w;
        }
        float4 r;
        r.x = 1.0f / (1.0f + expf(-a.x));
        r.y = 1.0f / (1.0f + expf(-a.y));
        r.z = 1.0f / (1.0f + expf(-a.z));
        r.w = 1.0f / (1.0f + expf(-a.w));
        *(float4*)&Lg[tt * RT_STR + lane * 4] = r;
    }
    __syncthreads();

    if (tid < RT_TOK) {
        const int t = t0 + tid;
        int id[TOPK]; float wv2[TOPK];
        unsigned gm; bool gt;
        const bool tight = route_core(
            [&](int e) { return Lg[tid * RT_STR + e]; }, bias, id, wv2, &gm, &gt);

        if (!tight) {
            sh_tight[tid] = 0u;
#pragma unroll
            for (int r = 0; r < TOPK; ++r) {
                out[(size_t)t * TOPK + r] = (float)id[r];
                out[(size_t)T_TOKENS * TOPK + (size_t)t * TOPK + r] = wv2[r];
            }
        } else {
            sh_tight[tid] = 1u | (gm << 16) | (gt ? (1u << 30) : 0u);
        }
    }
    __syncthreads();

    // ---- inline cleanup: exact fp32 recompute for tight tokens ----
    for (int tt = 0; tt < RT_TOK; ++tt) {
        const unsigned info = sh_tight[tt];    // uniform (LDS broadcast)
        if (info == 0u) continue;
        const int t          = t0 + tt;
        const unsigned gmask = (info >> 16) & 0xFFu;
        const bool gtight    = (info >> 30) & 1u;

        __syncthreads();                       // hrow/lg/sh_grp reuse guard
        if (tid < 4) {                         // tid-th set bit of gmask (4 set)
            unsigned mm = gmask; int g = 0;
            for (int i = 0; i <= tid; ++i) { g = __ffs(mm) - 1; mm &= mm - 1; }
            sh_grp[tid] = g;
        }
#pragma unroll
        for (int i = 0; i < 4; ++i) {
            const int f4 = i * 256 + tid;
            *(float4*)&hrow[f4 * 4] = *(const float4*)(hs + (size_t)t * HID + f4 * 4);
        }
        __syncthreads();

        bool full = gtight;
        if (!full) {
            const int eb = sh_grp[w] * GSIZE;
            for (int g2 = 0; g2 < 8; ++g2)
                dot4(hrow, wt, lg, eb + g2 * 4, lane);
            __syncthreads();                   // lg (128 allowed) complete
            // guard: need >=8 strictly positive allowed values for masked_top8
            const bool okpos = ((gmask >> (tid >> 5)) & 1) && (lg[tid] + bias[tid] > 0.0f);
            const int pos = __syncthreads_count(okpos ? 1 : 0);
            full = (pos < TOPK);
        }
        if (full) {
            for (int g = 0; g < 16; ++g)
                dot4(hrow, wt, lg, w * 64 + g * 4, lane);
            __syncthreads();
        }

        if (tid == 0) {
            int id[TOPK]; float wv[TOPK];
            if (full)
                route_core([&](int e) { return lg[e]; }, bias, id, wv);
            else
                masked_top8(lg, bias, gmask, id, wv);
            for (int r = 0; r < TOPK; ++r) {
                out[(size_t)t * TOPK + r] = (float)id[r];
                out[(size_t)T_TOKENS * TOPK + (size_t)t * TOPK + r] = wv[r];
            }
        }
    }
}

// =============== cleanup kernel (fallback tier only; R15 form) ===============
__global__ __launch_bounds__(256, 4)
void router_exact(const float* __restrict__ hs, const float* __restrict__ wt,
                  const float* __restrict__ bias, float* __restrict__ out,
                  const unsigned* __restrict__ wcnt, const unsigned* __restrict__ wlist,
                  unsigned cap)
{
    __shared__ float hrow[HID];
    __shared__ float lg[NEXP];
    __shared__ int   sh_grp[4];
    __shared__ int   sh_full;
    const unsigned count = min(*wcnt, cap);
    const int tid  = threadIdx.x;
    const int lane = tid & 63;
    const int w    = tid >> 6;

    for (unsigned b = blockIdx.x; b < count; b += gridDim.x) {
        __syncthreads();
        const unsigned ent = wlist[b];
        const int t          = (int)(ent & 0xFFFFu);
        const unsigned gmask = (ent >> 16) & 0xFFu;
        const bool gtight    = (ent >> 30) & 1u;

        if (tid < 4) {
            unsigned mm = gmask; int g = 0;
            for (int i = 0; i <= tid; ++i) { g = __ffs(mm) - 1; mm &= mm - 1; }
            sh_grp[tid] = g;
        }
        if (tid == 0) sh_full = gtight ? 1 : 0;

#pragma unroll
        for (int i = 0; i < 4; ++i) {
            const int f4 = i * 256 + tid;
            *(float4*)&hrow[f4 * 4] = *(const float4*)(hs + (size_t)t * HID + f4 * 4);
        }
        __syncthreads();

        bool full = (sh_full != 0);
        if (!full) {
            const int eb = sh_grp[w] * GSIZE;
            for (int g2 = 0; g2 < 8; ++g2)
                dot4(hrow, wt, lg, eb + g2 * 4, lane);
            __syncthreads();
            if (tid == 0) {
                int pos = 0;
                for (int e = 0; e < NEXP; ++e)
                    if (((gmask >> (e >> 5)) & 1) && lg[e] + bias[e] > 0.0f) ++pos;
                sh_full = (pos < TOPK) ? 1 : 0;
            }
            __syncthreads();
            full = (sh_full != 0);
        }
        if (full) {
            for (int g = 0; g < 16; ++g)
                dot4(hrow, wt, lg, w * 64 + g * 4, lane);
            __syncthreads();
        }

        if (tid == 0) {
            int id[TOPK]; float wv[TOPK];
            if (full)
                route_core([&](int e) { return lg[e]; }, bias, id, wv);
            else
                masked_top8(lg, bias, gmask, id, wv);
            for (int r = 0; r < TOPK; ++r) {
                out[(size_t)t * TOPK + r] = (float)id[r];
                out[(size_t)T_TOKENS * TOPK + (size_t)t * TOPK + r] = wv[r];
            }
        }
    }
}

// =============== fallback monolith (R5-validated; packs wlist) ===============
__global__ __launch_bounds__(512, 1)
void router_mono(const float* __restrict__ hs, const float* __restrict__ wt,
                 const float* __restrict__ bias, float* __restrict__ out,
                 unsigned* __restrict__ wcnt, unsigned* __restrict__ wlist, unsigned cap)
{
    __shared__ float smem[16384];
    ushort* u16 = (ushort*)smem;
    float*  Lg  = smem;

    const int tid  = threadIdx.x;
    const int lane = tid & 63;
    const int w    = tid >> 6;
    const int t0   = blockIdx.x * 64;
    const int ar   = tid >> 3;
    const int aq   = tid & 7;

    f32x4 acc[4][2];
#pragma unroll
    for (int i = 0; i < 4; ++i)
#pragma unroll
        for (int j = 0; j < 2; ++j) acc[i][j] = (f32x4)0.0f;

    float4 ra, rb[4];
    ra = *(const float4*)(hs + (size_t)(t0 + ar) * HID + aq * 4);
#pragma unroll
    for (int s = 0; s < 4; ++s)
        rb[s] = *(const float4*)(wt + (size_t)(ar + s * 64) * HID + aq * 4);

    for (int ks = 0; ks < HID / BK; ++ks) {
        __syncthreads();
        {
            uint h01, h23, l01, l23;
            split4(ra, h01, h23, l01, l23);
            const int eo = stoffA(ar, aq);
            uint2 hv; hv.x = h01; hv.y = h23;
            uint2 lv; lv.x = l01; lv.y = l23;
            *(uint2*)&u16[0 + eo] = hv;
            *(uint2*)&u16[2048 + eo] = lv;
        }
#pragma unroll
        for (int s = 0; s < 4; ++s) {
            const int e = ar + s * 64;
            uint h01, h23, l01, l23;
            split4(rb[s], h01, h23, l01, l23);
            const int eo = stoffA(e, aq);
            uint2 hv; hv.x = h01; hv.y = h23;
            uint2 lv; lv.x = l01; lv.y = l23;
            *(uint2*)&u16[4096 + eo] = hv;
            *(uint2*)&u16[12288 + eo] = lv;
        }
        __syncthreads();
        if (ks + 1 < HID / BK) {
            const int k0 = (ks + 1) * BK;
            ra = *(const float4*)(hs + (size_t)(t0 + ar) * HID + k0 + aq * 4);
#pragma unroll
            for (int s = 0; s < 4; ++s)
                rb[s] = *(const float4*)(wt + (size_t)(ar + s * 64) * HID + k0 + aq * 4);
        }
        const int fo = froffL(lane);
        bf16x8 ah[4], al[4];
#pragma unroll
        for (int rt = 0; rt < 4; ++rt) {
            ah[rt] = *(const bf16x8*)&u16[0 + rt * 512 + fo];
            al[rt] = *(const bf16x8*)&u16[2048 + rt * 512 + fo];
        }
#pragma unroll
        for (int c = 0; c < 2; ++c) {
            const int ct = w * 2 + c;
            const bf16x8 bh = *(const bf16x8*)&u16[4096 + ct * 512 + fo];
            const bf16x8 bl = *(const bf16x8*)&u16[12288 + ct * 512 + fo];
#pragma unroll
            for (int rt = 0; rt < 4; ++rt) {
                acc[rt][c] = __builtin_amdgcn_mfma_f32_16x16x32_bf16(ah[rt], bh, acc[rt][c], 0, 0, 0);
                acc[rt][c] = __builtin_amdgcn_mfma_f32_16x16x32_bf16(ah[rt], bl, acc[rt][c], 0, 0, 0);
                acc[rt][c] = __builtin_amdgcn_mfma_f32_16x16x32_bf16(al[rt], bh, acc[rt][c], 0, 0, 0);
            }
        }
    }
    __syncthreads();
#pragma unroll
    for (int rt = 0; rt < 4; ++rt)
#pragma unroll
        for (int c = 0; c < 2; ++c) {
            const int col  = w * 32 + c * 16 + (lane & 15);
            const int rowb = rt * 16 + (lane >> 4) * 4;
#pragma unroll
            for (int j = 0; j < 4; ++j) {
                const int row = rowb + j;
                Lg[col * 64 + ((row + col) & 63)] = 1.0f / (1.0f + expf(-acc[rt][c][j]));
            }
        }
    __syncthreads();

    if (tid < 64) {
        const int t = t0 + tid;
        int id[TOPK]; float wv[TOPK];
        unsigned gm; bool gt;
        const bool tight = route_core(
            [&](int e) { return Lg[e * 64 + ((tid + e) & 63)]; }, bias, id, wv, &gm, &gt);
#pragma unroll
        for (int r = 0; r < TOPK; ++r) {
            out[(size_t)t * TOPK + r] = (float)id[r];
            out[(size_t)T_TOKENS * TOPK + (size_t)t * TOPK + r] = wv[r];
        }
        if (tight) {
            bool queued = false;
            if (wcnt) {
                const unsigned pos = atomicAdd(wcnt, 1u);
                if (pos < cap) {
                    wlist[pos] = (unsigned)t | (gm << 16) | (gt ? (1u << 30) : 0u);
                    queued = true;
                }
            }
            if (!queued) exact_token(hs, wt, bias, out, t);
        }
    }
}

extern "C" void kernel_launch(void* const* d_in, const int* in_sizes, int n_in,
                              void* d_out, int out_size, void* d_ws, size_t ws_size,
                              hipStream_t stream) {
    const float* hs   = (const float*)d_in[0];   // [16384, 4096] f32
    const float* wt   = (const float*)d_in[1];   // [256, 4096]   f32
    const float* bias = (const float*)d_in[2];   // [256]         f32
    float* out = (float*)d_out;
    (void)in_sizes; (void)n_in; (void)out_size;

    const size_t PW_BYTES = (size_t)SPLITK * T_TOKENS * NEXP * 4;   // 64 MB
    const size_t WQ_BYTES = (size_t)2 * WQ_LIMB * 2;                // 4 MB
    const size_t NEED = PW_BYTES + WQ_BYTES;

    if (ws_size >= NEED) {
        float*  pw = (float*)d_ws;
        ushort* wq = (ushort*)((char*)d_ws + PW_BYTES);
        conv_weight<<<512, 256, 0, stream>>>(wt, wq);
        router_gemm<<<(T_TOKENS / BM) * SPLITK, 256, 0, stream>>>(hs, wq, pw);
        router_route<<<T_TOKENS / RT_TOK, 256, 0, stream>>>(pw, hs, wt, bias, out);
    } else if (ws_size >= 8) {
        unsigned cap = (unsigned)((ws_size - 4) / 4);
        if (cap > T_TOKENS) cap = T_TOKENS;
        unsigned* wcnt  = (unsigned*)d_ws;
        unsigned* wlist = wcnt + 1;
        hipMemsetAsync(d_ws, 0, sizeof(unsigned), stream);
        router_mono<<<T_TOKENS / 64, 512, 0, stream>>>(hs, wt, bias, out, wcnt, wlist, cap);
        router_exact<<<2048, 256, 0, stream>>>(hs, wt, bias, out, wcnt, wlist, cap);
    } else {
        router_mono<<<T_TOKENS / 64, 512, 0, stream>>>(hs, wt, bias, out,
                                                       nullptr, nullptr, 0u);
    }
}

// Round 18
// 365.132 us; speedup vs baseline: 1.3256x; 1.2796x over previous
//
#include <hip/hip_runtime.h>
#include <math.h>

#define T_TOKENS 16384
#define HID      4096
#define NEXP     256
#define NGROUP   8
#define GSIZE    32
#define TOPKG    4
#define TOPK     8
#define RSCALE   2.5f

#define TAU   1.5e-5f    // expert-score margin (R13-R17-validated, 9 sigma)
#define TAUG  2.5e-5f    // group-score margin

// ---- split-K GEMM config (R9/R14-validated) ----
#define BM     64
#define BK     32
#define SPLITK 4
#define KSPAN  (HID / SPLITK)    // 1024
#define NKS    (KSPAN / BK)      // 32 K-steps per block
#define NSG    (HID / BK)        // 128 global K-steps

// LDS staging (ushort units), UNPADDED frag-major (R9-validated)
#define A_HI   0
#define A_LO   2048
#define B_HI   4096
#define B_LO   12288
#define STG_TOT 20480            // 40 KB -> 4 blocks/CU

#define WQ_LIMB (NSG * 8192)
#define RT_TOK 16                // route tokens/block (R14-validated)
#define RT_STR 260               // Lg row stride (16B-aligned)

typedef __attribute__((ext_vector_type(8))) short bf16x8;
typedef __attribute__((ext_vector_type(4))) float f32x4;

__device__ __forceinline__ int stoffA(int r, int q) {
    return (r >> 4) * 512 + (q >> 1) * 128 + (r & 15) * 8 + (q & 1) * 4;
}
__device__ __forceinline__ int froffL(int lane) {
    return (lane >> 4) * 128 + (lane & 15) * 8;
}

__device__ __forceinline__ void gload16(const void* g, void* l) {
    __builtin_amdgcn_global_load_lds(
        (const __attribute__((address_space(1))) void*)g,
        (__attribute__((address_space(3))) void*)l, 16, 0, 0);
}

// Split float4 into packed bf16 hi (RNE) and lo (RNE of exact residual).
__device__ __forceinline__ void split4(const float4 v, uint& h01, uint& h23,
                                       uint& l01, uint& l23) {
    const uint u0 = __float_as_uint(v.x) + 0x8000u;
    const uint u1 = __float_as_uint(v.y) + 0x8000u;
    const uint u2 = __float_as_uint(v.z) + 0x8000u;
    const uint u3 = __float_as_uint(v.w) + 0x8000u;
    h01 = __builtin_amdgcn_perm(u1, u0, 0x07060302u);
    h23 = __builtin_amdgcn_perm(u3, u2, 0x07060302u);
    const float f0 = v.x - __uint_as_float(u0 & 0xFFFF0000u);
    const float f1 = v.y - __uint_as_float(u1 & 0xFFFF0000u);
    const float f2 = v.z - __uint_as_float(u2 & 0xFFFF0000u);
    const float f3 = v.w - __uint_as_float(u3 & 0xFFFF0000u);
    l01 = __builtin_amdgcn_perm(__float_as_uint(f1) + 0x8000u,
                                __float_as_uint(f0) + 0x8000u, 0x07060302u);
    l23 = __builtin_amdgcn_perm(__float_as_uint(f3) + 0x8000u,
                                __float_as_uint(f2) + 0x8000u, 0x07060302u);
}

// ---- shared routing decision (validated R5-R17); exports gmask/gtight ----
template <class SC>
__device__ __forceinline__ bool route_core(SC sc, const float* __restrict__ bias,
                                           int* id, float* wv,
                                           unsigned* ogmask = nullptr,
                                           bool* ogtight = nullptr)
{
    float gs[NGROUP];
#pragma unroll
    for (int g = 0; g < NGROUP; ++g) {
        float m1 = -1e30f, m2 = -1e30f;
        for (int i = 0; i < GSIZE; ++i) {
            const int e = g * GSIZE + i;
            const float v = sc(e) + bias[e];
            if (v > m1)      { m2 = m1; m1 = v; }
            else if (v > m2) { m2 = v; }
        }
        gs[g] = m1 + m2;
    }

    unsigned gmask = 0;
    float g4 = -1e30f;
#pragma unroll
    for (int r = 0; r < TOPKG; ++r) {
        int bi = 0; float bv = -1e30f;
#pragma unroll
        for (int g = 0; g < NGROUP; ++g) {
            const bool taken = (gmask >> g) & 1;
            if (!taken && gs[g] > bv) { bv = gs[g]; bi = g; }
        }
        gmask |= 1u << bi;
        g4 = bv;
    }
    float g5 = -1e30f;
#pragma unroll
    for (int g = 0; g < NGROUP; ++g)
        if (!((gmask >> g) & 1) && gs[g] > g5) g5 = gs[g];

    float val[TOPK + 1]; int vid[TOPK + 1];
#pragma unroll
    for (int r = 0; r <= TOPK; ++r) { val[r] = -1e30f; vid[r] = 0; }
    for (int e = 0; e < NEXP; ++e) {
        const bool allowed = (gmask >> (e >> 5)) & 1;
        const float v = allowed ? (sc(e) + bias[e]) : 0.0f;
        if (v > val[TOPK]) {
#pragma unroll
            for (int p = TOPK; p >= 1; --p) {
                if (v > val[p - 1])  { val[p] = val[p - 1]; vid[p] = vid[p - 1]; }
                else if (v > val[p]) { val[p] = v;          vid[p] = e; }
            }
            if (v > val[0]) { val[0] = v; vid[0] = e; }
        }
    }

    const bool gtight = (g4 - g5 < TAUG);
    bool tight = gtight;
#pragma unroll
    for (int i = 0; i < TOPK; ++i) tight |= (val[i] - val[i + 1] < TAU);

    float sum = 0.0f;
#pragma unroll
    for (int r = 0; r < TOPK; ++r) { id[r] = vid[r]; wv[r] = sc(vid[r]); sum += wv[r]; }
    const float inv = RSCALE / (sum + 1e-20f);
#pragma unroll
    for (int r = 0; r < TOPK; ++r) wv[r] *= inv;

    if (ogmask)  *ogmask  = gmask;
    if (ogtight) *ogtight = gtight;
    return tight;
}

// masked top-8 with FIXED gmask over exact sigmoid scores (R15-validated)
__device__ __forceinline__ void masked_top8(const float* __restrict__ lg,
                                            const float* __restrict__ bias,
                                            unsigned gmask, int* id, float* wv)
{
    float val[TOPK]; int vid[TOPK];
#pragma unroll
    for (int r = 0; r < TOPK; ++r) { val[r] = -1e30f; vid[r] = 0; }
    for (int e = 0; e < NEXP; ++e) {
        const bool allowed = (gmask >> (e >> 5)) & 1;
        const float v = allowed ? (lg[e] + bias[e]) : 0.0f;
        if (v > val[TOPK - 1]) {
#pragma unroll
            for (int p = TOPK - 1; p >= 1; --p) {
                if (v > val[p - 1])  { val[p] = val[p - 1]; vid[p] = vid[p - 1]; }
                else if (v > val[p]) { val[p] = v;          vid[p] = e; }
            }
            if (v > val[0]) { val[0] = v; vid[0] = e; }
        }
    }
    float sum = 0.0f;
#pragma unroll
    for (int r = 0; r < TOPK; ++r) { id[r] = vid[r]; wv[r] = lg[vid[r]]; sum += wv[r]; }
    const float inv = RSCALE / (sum + 1e-20f);
#pragma unroll
    for (int r = 0; r < TOPK; ++r) wv[r] *= inv;
}

// exact fp32 recompute + route for one token (cold fallback only)
__device__ void exact_token(const float* __restrict__ hs, const float* __restrict__ wt,
                            const float* __restrict__ bias, float* __restrict__ out, int t)
{
    float lg[NEXP];
    const float* hrow = hs + (size_t)t * HID;
    for (int e = 0; e < NEXP; ++e) {
        const float* wr = wt + (size_t)e * HID;
        float a = 0.0f;
        for (int k = 0; k < HID; k += 4) {
            const float4 x = *(const float4*)(hrow + k);
            const float4 b = *(const float4*)(wr + k);
            a = fmaf(x.x, b.x, a); a = fmaf(x.y, b.y, a);
            a = fmaf(x.z, b.z, a); a = fmaf(x.w, b.w, a);
        }
        lg[e] = 1.0f / (1.0f + expf(-a));
    }
    int id[TOPK]; float wv[TOPK];
    route_core([&](int e) { return lg[e]; }, bias, id, wv);
    for (int r = 0; r < TOPK; ++r) {
        out[(size_t)t * TOPK + r] = (float)id[r];
        out[(size_t)T_TOKENS * TOPK + (size_t)t * TOPK + r] = wv[r];
    }
}

// =============== one-shot weight conversion v2 (R16, coalesced writes) ===============
__global__ __launch_bounds__(256, 8)
void conv_weight(const float* __restrict__ wt, ushort* __restrict__ wq)
{
    const int g    = blockIdx.x * 256 + threadIdx.x;   // 131072 threads
    const int e_lo = g & 15;
    const int kch  = (g >> 4) & 3;
    const int e_hi = (g >> 6) & 15;
    const int sg   = g >> 10;                          // 0..127
    const int e    = e_hi * 16 + e_lo;
    const int k0   = sg * 32 + kch * 8;

    const float4 v0 = *(const float4*)(wt + (size_t)e * HID + k0);
    const float4 v1 = *(const float4*)(wt + (size_t)e * HID + k0 + 4);
    uint h01, h23, l01, l23, h45, h67, l45, l67;
    split4(v0, h01, h23, l01, l23);
    split4(v1, h45, h67, l45, l67);

    const size_t idx = (size_t)sg * 8192 + (size_t)(e_hi * 512 + kch * 128 + e_lo * 8);
    uint4 hv; hv.x = h01; hv.y = h23; hv.z = h45; hv.w = h67;
    uint4 lv; lv.x = l01; lv.y = l23; lv.z = l45; lv.w = l67;
    *(uint4*)&wq[idx] = hv;
    *(uint4*)&wq[(size_t)WQ_LIMB + idx] = lv;
}

// =============== split-K GEMM v2 (R14-verbatim) ===============
__global__ __launch_bounds__(256, 4)
void router_gemm(const float* __restrict__ hs, const ushort* __restrict__ wq,
                 float* __restrict__ pw)
{
    __shared__ ushort u16[STG_TOT];

    const int tid  = threadIdx.x;
    const int lane = tid & 63;
    const int w    = tid >> 6;
    const int b    = blockIdx.x;
    const int m    = (b >> 5) * 8 + (b & 7);
    const int sk   = (b >> 3) & 3;
    const int t0   = m * BM;
    const int kb0  = sk * KSPAN;
    const int r0   = tid >> 3;
    const int q    = tid & 7;

    const ushort* wq_hi = wq;
    const ushort* wq_lo = wq + WQ_LIMB;

    f32x4 acc[4][4];
#pragma unroll
    for (int i = 0; i < 4; ++i)
#pragma unroll
        for (int j = 0; j < 4; ++j) acc[i][j] = (f32x4)0.0f;

    float4 ra[2];
#pragma unroll
    for (int s = 0; s < 2; ++s)
        ra[s] = *(const float4*)(hs + (size_t)(t0 + r0 + 32 * s) * HID + kb0 + q * 4);

    for (int ks = 0; ks < NKS; ++ks) {
        const int sg = sk * NKS + ks;
        __syncthreads();

        {
            const size_t gb = (size_t)sg * 8192 + (size_t)(w * 4) * 512 + (size_t)lane * 8;
#pragma unroll
            for (int i = 0; i < 4; ++i) {
                gload16(wq_hi + gb + i * 512, &u16[B_HI + (w * 4 + i) * 512]);
                gload16(wq_lo + gb + i * 512, &u16[B_LO + (w * 4 + i) * 512]);
            }
        }
#pragma unroll
        for (int s = 0; s < 2; ++s) {
            const int r = r0 + 32 * s;
            uint h01, h23, l01, l23;
            split4(ra[s], h01, h23, l01, l23);
            const int eo = stoffA(r, q);
            uint2 hv; hv.x = h01; hv.y = h23;
            uint2 lv; lv.x = l01; lv.y = l23;
            *(uint2*)&u16[A_HI + eo] = hv;
            *(uint2*)&u16[A_LO + eo] = lv;
        }
        __syncthreads();

        if (ks + 1 < NKS) {
            const int kb = kb0 + (ks + 1) * BK;
#pragma unroll
            for (int s = 0; s < 2; ++s)
                ra[s] = *(const float4*)(hs + (size_t)(t0 + r0 + 32 * s) * HID + kb + q * 4);
        }

        const int fo = froffL(lane);
        bf16x8 ah[4], al[4];
#pragma unroll
        for (int rt = 0; rt < 4; ++rt) {
            ah[rt] = *(const bf16x8*)&u16[A_HI + rt * 512 + fo];
            al[rt] = *(const bf16x8*)&u16[A_LO + rt * 512 + fo];
        }
#pragma unroll
        for (int c = 0; c < 4; ++c) {
            const int ct = w * 4 + c;
            const bf16x8 bh = *(const bf16x8*)&u16[B_HI + ct * 512 + fo];
            const bf16x8 bl = *(const bf16x8*)&u16[B_LO + ct * 512 + fo];
#pragma unroll
            for (int rt = 0; rt < 4; ++rt) {
                acc[rt][c] = __builtin_amdgcn_mfma_f32_16x16x32_bf16(ah[rt], bh, acc[rt][c], 0, 0, 0);
                acc[rt][c] = __builtin_amdgcn_mfma_f32_16x16x32_bf16(ah[rt], bl, acc[rt][c], 0, 0, 0);
                acc[rt][c] = __builtin_amdgcn_mfma_f32_16x16x32_bf16(al[rt], bh, acc[rt][c], 0, 0, 0);
            }
        }
    }

#pragma unroll
    for (int rt = 0; rt < 4; ++rt)
#pragma unroll
        for (int c = 0; c < 4; ++c) {
            const int col  = w * 64 + c * 16 + (lane & 15);
            const int rowb = rt * 16 + (lane >> 4) * 4;
#pragma unroll
            for (int j = 0; j < 4; ++j)
                pw[((size_t)(sk * T_TOKENS) + t0 + rowb + j) * NEXP + col] = acc[rt][c][j];
        }
}

// =============== routing v3 (R16): vectorized pw reads + packed wlist ===============
__global__ __launch_bounds__(256, 4)
void router_route(const float* __restrict__ pw, const float* __restrict__ bias,
                  float* __restrict__ out,
                  unsigned* __restrict__ wcnt, unsigned* __restrict__ wlist,
                  unsigned cap)
{
    __shared__ float Lg[RT_TOK * RT_STR];  // 16.25 KB, row-major [token][expert]
    const int tid  = threadIdx.x;
    const int b    = blockIdx.x;
    const int x    = b & 7;
    const int rest = b >> 3;
    const int m    = (rest >> 2) * 8 + x;   // XCD-matched (R14)
    const int sub  = rest & 3;
    const int t0   = m * BM + sub * RT_TOK;

    const int wv = tid >> 6;               // wave -> 4 tokens
    const int l  = tid & 63;               // lane -> 4 experts

#pragma unroll
    for (int j = 0; j < 4; ++j) {
        const int tt = wv * 4 + j;
        const int t  = t0 + tt;
        float4 a = {0.0f, 0.0f, 0.0f, 0.0f};
#pragma unroll
        for (int s = 0; s < SPLITK; ++s) {  // FIXED order (deterministic)
            const float4 v = *(const float4*)&pw[((size_t)(s * T_TOKENS) + t) * NEXP + l * 4];
            a.x += v.x; a.y += v.y; a.z += v.z; a.w += v.w;
        }
        float4 r;
        r.x = 1.0f / (1.0f + expf(-a.x));
        r.y = 1.0f / (1.0f + expf(-a.y));
        r.z = 1.0f / (1.0f + expf(-a.z));
        r.w = 1.0f / (1.0f + expf(-a.w));
        *(float4*)&Lg[tt * RT_STR + l * 4] = r;
    }
    __syncthreads();

    if (tid < RT_TOK) {
        const int t = t0 + tid;
        int id[TOPK]; float wv2[TOPK];
        unsigned gm; bool gt;
        const bool tight = route_core(
            [&](int e) { return Lg[tid * RT_STR + e]; }, bias, id, wv2, &gm, &gt);

#pragma unroll
        for (int r = 0; r < TOPK; ++r) {
            out[(size_t)t * TOPK + r] = (float)id[r];
            out[(size_t)T_TOKENS * TOPK + (size_t)t * TOPK + r] = wv2[r];
        }
        if (tight) {
            const unsigned pos = atomicAdd(wcnt, 1u);
            if (pos < cap)
                wlist[pos] = (unsigned)t | (gm << 16) | (gt ? (1u << 30) : 0u);
        }
    }
}

// 4-expert exact dot — R15 simple form, unroll 8 (deeper compiler load batching)
__device__ __forceinline__ void dot4(const float* __restrict__ hrow,
                                     const float* __restrict__ wt,
                                     float* __restrict__ lg, int e0, int lane)
{
    float a[4] = {0.0f, 0.0f, 0.0f, 0.0f};
#pragma unroll 8
    for (int j = 0; j < 16; ++j) {
        const int f4 = j * 64 + lane;
        const float4 h = *(const float4*)&hrow[f4 * 4];
#pragma unroll
        for (int p = 0; p < 4; ++p) {
            const float4 v = *(const float4*)(wt + (size_t)(e0 + p) * HID + f4 * 4);
            a[p] = fmaf(h.x, v.x, a[p]); a[p] = fmaf(h.y, v.y, a[p]);
            a[p] = fmaf(h.z, v.z, a[p]); a[p] = fmaf(h.w, v.w, a[p]);
        }
    }
#pragma unroll
    for (int p = 0; p < 4; ++p)
#pragma unroll
        for (int d = 1; d < 64; d <<= 1)
            a[p] += __shfl_xor(a[p], d, 64);
    if (lane == 0) {
#pragma unroll
        for (int p = 0; p < 4; ++p)
            lg[e0 + p] = 1.0f / (1.0f + expf(-a[p]));
    }
}

// =============== cleanup v6' (R15 control flow; wider VGPR budget) ===============
__global__ __launch_bounds__(256, 2)
void router_exact(const float* __restrict__ hs, const float* __restrict__ wt,
                  const float* __restrict__ bias, float* __restrict__ out,
                  const unsigned* __restrict__ wcnt, const unsigned* __restrict__ wlist,
                  unsigned cap)
{
    __shared__ float hrow[HID];          // 16 KB
    __shared__ float lg[NEXP];           // 1 KB
    __shared__ int   sh_grp[4];
    __shared__ int   sh_full;
    const unsigned count = min(*wcnt, cap);
    const int tid  = threadIdx.x;
    const int lane = tid & 63;
    const int w    = tid >> 6;

    for (unsigned b = blockIdx.x; b < count; b += gridDim.x) {
        __syncthreads();                 // guard reuse across passes
        const unsigned ent = wlist[b];
        const int t          = (int)(ent & 0xFFFFu);
        const unsigned gmask = (ent >> 16) & 0xFFu;
        const bool gtight    = (ent >> 30) & 1u;

        if (tid < 4) {                   // tid-th set bit of gmask (exactly 4 set)
            unsigned mm = gmask; int g = 0;
            for (int i = 0; i <= tid; ++i) { g = __ffs(mm) - 1; mm &= mm - 1; }
            sh_grp[tid] = g;
        }
        if (tid == 0) sh_full = gtight ? 1 : 0;

#pragma unroll
        for (int i = 0; i < 4; ++i) {
            const int f4 = i * 256 + tid;
            *(float4*)&hrow[f4 * 4] = *(const float4*)(hs + (size_t)t * HID + f4 * 4);
        }
        __syncthreads();

        bool full = (sh_full != 0);
        if (!full) {
            const int eb = sh_grp[w] * GSIZE;
            for (int g2 = 0; g2 < 8; ++g2)
                dot4(hrow, wt, lg, eb + g2 * 4, lane);
            __syncthreads();
            if (tid == 0) {
                int pos = 0;
                for (int e = 0; e < NEXP; ++e)
                    if (((gmask >> (e >> 5)) & 1) && lg[e] + bias[e] > 0.0f) ++pos;
                sh_full = (pos < TOPK) ? 1 : 0;
            }
            __syncthreads();
            full = (sh_full != 0);
        }
        if (full) {
            for (int g = 0; g < 16; ++g)
                dot4(hrow, wt, lg, w * 64 + g * 4, lane);
            __syncthreads();
        }

        if (tid == 0) {
            int id[TOPK]; float wv[TOPK];
            if (full)
                route_core([&](int e) { return lg[e]; }, bias, id, wv);
            else
                masked_top8(lg, bias, gmask, id, wv);
            for (int r = 0; r < TOPK; ++r) {
                out[(size_t)t * TOPK + r] = (float)id[r];
                out[(size_t)T_TOKENS * TOPK + (size_t)t * TOPK + r] = wv[r];
            }
        }
    }
}

// =============== fallback monolith (R5-validated; packs wlist) ===============
__global__ __launch_bounds__(512, 1)
void router_mono(const float* __restrict__ hs, const float* __restrict__ wt,
                 const float* __restrict__ bias, float* __restrict__ out,
                 unsigned* __restrict__ wcnt, unsigned* __restrict__ wlist, unsigned cap)
{
    __shared__ float smem[16384];
    ushort* u16 = (ushort*)smem;
    float*  Lg  = smem;

    const int tid  = threadIdx.x;
    const int lane = tid & 63;
    const int w    = tid >> 6;
    const int t0   = blockIdx.x * 64;
    const int ar   = tid >> 3;
    const int aq   = tid & 7;

    f32x4 acc[4][2];
#pragma unroll
    for (int i = 0; i < 4; ++i)
#pragma unroll
        for (int j = 0; j < 2; ++j) acc[i][j] = (f32x4)0.0f;

    float4 ra, rb[4];
    ra = *(const float4*)(hs + (size_t)(t0 + ar) * HID + aq * 4);
#pragma unroll
    for (int s = 0; s < 4; ++s)
        rb[s] = *(const float4*)(wt + (size_t)(ar + s * 64) * HID + aq * 4);

    for (int ks = 0; ks < HID / BK; ++ks) {
        __syncthreads();
        {
            uint h01, h23, l01, l23;
            split4(ra, h01, h23, l01, l23);
            const int eo = stoffA(ar, aq);
            uint2 hv; hv.x = h01; hv.y = h23;
            uint2 lv; lv.x = l01; lv.y = l23;
            *(uint2*)&u16[0 + eo] = hv;
            *(uint2*)&u16[2048 + eo] = lv;
        }
#pragma unroll
        for (int s = 0; s < 4; ++s) {
            const int e = ar + s * 64;
            uint h01, h23, l01, l23;
            split4(rb[s], h01, h23, l01, l23);
            const int eo = stoffA(e, aq);
            uint2 hv; hv.x = h01; hv.y = h23;
            uint2 lv; lv.x = l01; lv.y = l23;
            *(uint2*)&u16[4096 + eo] = hv;
            *(uint2*)&u16[12288 + eo] = lv;
        }
        __syncthreads();
        if (ks + 1 < HID / BK) {
            const int k0 = (ks + 1) * BK;
            ra = *(const float4*)(hs + (size_t)(t0 + ar) * HID + k0 + aq * 4);
#pragma unroll
            for (int s = 0; s < 4; ++s)
                rb[s] = *(const float4*)(wt + (size_t)(ar + s * 64) * HID + k0 + aq * 4);
        }
        const int fo = froffL(lane);
        bf16x8 ah[4], al[4];
#pragma unroll
        for (int rt = 0; rt < 4; ++rt) {
            ah[rt] = *(const bf16x8*)&u16[0 + rt * 512 + fo];
            al[rt] = *(const bf16x8*)&u16[2048 + rt * 512 + fo];
        }
#pragma unroll
        for (int c = 0; c < 2; ++c) {
            const int ct = w * 2 + c;
            const bf16x8 bh = *(const bf16x8*)&u16[4096 + ct * 512 + fo];
            const bf16x8 bl = *(const bf16x8*)&u16[12288 + ct * 512 + fo];
#pragma unroll
            for (int rt = 0; rt < 4; ++rt) {
                acc[rt][c] = __builtin_amdgcn_mfma_f32_16x16x32_bf16(ah[rt], bh, acc[rt][c], 0, 0, 0);
                acc[rt][c] = __builtin_amdgcn_mfma_f32_16x16x32_bf16(ah[rt], bl, acc[rt][c], 0, 0, 0);
                acc[rt][c] = __builtin_amdgcn_mfma_f32_16x16x32_bf16(al[rt], bh, acc[rt][c], 0, 0, 0);
            }
        }
    }
    __syncthreads();
#pragma unroll
    for (int rt = 0; rt < 4; ++rt)
#pragma unroll
        for (int c = 0; c < 2; ++c) {
            const int col  = w * 32 + c * 16 + (lane & 15);
            const int rowb = rt * 16 + (lane >> 4) * 4;
#pragma unroll
            for (int j = 0; j < 4; ++j) {
                const int row = rowb + j;
                Lg[col * 64 + ((row + col) & 63)] = 1.0f / (1.0f + expf(-acc[rt][c][j]));
            }
        }
    __syncthreads();

    if (tid < 64) {
        const int t = t0 + tid;
        int id[TOPK]; float wv[TOPK];
        unsigned gm; bool gt;
        const bool tight = route_core(
            [&](int e) { return Lg[e * 64 + ((tid + e) & 63)]; }, bias, id, wv, &gm, &gt);
#pragma unroll
        for (int r = 0; r < TOPK; ++r) {
            out[(size_t)t * TOPK + r] = (float)id[r];
            out[(size_t)T_TOKENS * TOPK + (size_t)t * TOPK + r] = wv[r];
        }
        if (tight) {
            bool queued = false;
            if (wcnt) {
                const unsigned pos = atomicAdd(wcnt, 1u);
                if (pos < cap) {
                    wlist[pos] = (unsigned)t | (gm << 16) | (gt ? (1u << 30) : 0u);
                    queued = true;
                }
            }
            if (!queued) exact_token(hs, wt, bias, out, t);
        }
    }
}

extern "C" void kernel_launch(void* const* d_in, const int* in_sizes, int n_in,
                              void* d_out, int out_size, void* d_ws, size_t ws_size,
                              hipStream_t stream) {
    const float* hs   = (const float*)d_in[0];   // [16384, 4096] f32
    const float* wt   = (const float*)d_in[1];   // [256, 4096]   f32
    const float* bias = (const float*)d_in[2];   // [256]         f32
    float* out = (float*)d_out;
    (void)in_sizes; (void)n_in; (void)out_size;

    const size_t PW_BYTES = (size_t)SPLITK * T_TOKENS * NEXP * 4;   // 64 MB
    const size_t WQ_BYTES = (size_t)2 * WQ_LIMB * 2;                // 4 MB
    const size_t NEED = PW_BYTES + WQ_BYTES + 4 + (size_t)T_TOKENS * 4;

    if (ws_size >= NEED) {
        float*    pw    = (float*)d_ws;
        ushort*   wq    = (ushort*)((char*)d_ws + PW_BYTES);
        unsigned* wcnt  = (unsigned*)((char*)d_ws + PW_BYTES + WQ_BYTES);
        unsigned* wlist = wcnt + 1;
        hipMemsetAsync(wcnt, 0, sizeof(unsigned), stream);
        conv_weight<<<512, 256, 0, stream>>>(wt, wq);
        router_gemm<<<(T_TOKENS / BM) * SPLITK, 256, 0, stream>>>(hs, wq, pw);
        router_route<<<T_TOKENS / RT_TOK, 256, 0, stream>>>(pw, bias, out, wcnt, wlist,
                                                            (unsigned)T_TOKENS);
        router_exact<<<2048, 256, 0, stream>>>(hs, wt, bias, out, wcnt, wlist,
                                               (unsigned)T_TOKENS);
    } else if (ws_size >= 8) {
        unsigned cap = (unsigned)((ws_size - 4) / 4);
        if (cap > T_TOKENS) cap = T_TOKENS;
        unsigned* wcnt  = (unsigned*)d_ws;
        unsigned* wlist = wcnt + 1;
        hipMemsetAsync(d_ws, 0, sizeof(unsigned), stream);
        router_mono<<<T_TOKENS / 64, 512, 0, stream>>>(hs, wt, bias, out, wcnt, wlist, cap);
        router_exact<<<2048, 256, 0, stream>>>(hs, wt, bias, out, wcnt, wlist, cap);
    } else {
        router_mono<<<T_TOKENS / 64, 512, 0, stream>>>(hs, wt, bias, out,
                                                       nullptr, nullptr, 0u);
    }
}

// Round 19
// 336.971 us; speedup vs baseline: 1.4364x; 1.0836x over previous
//
#include <hip/hip_runtime.h>
#include <math.h>

#define T_TOKENS 16384
#define HID      4096
#define NEXP     256
#define NGROUP   8
#define GSIZE    32
#define TOPKG    4
#define TOPK     8
#define RSCALE   2.5f

#define TAU   1.5e-5f    // expert-score margin (R13-validated)
#define TAUG  2.5e-5f    // group-score margin  (R13-validated)

// ---- split-K GEMM config (R9-validated) ----
#define BM     64
#define BK     32
#define SPLITK 4
#define KSPAN  (HID / SPLITK)    // 1024
#define NKS    (KSPAN / BK)      // 32 K-steps per block
#define NSG    (HID / BK)        // 128 global K-steps

// LDS staging (ushort units), UNPADDED frag-major (R9-validated):
//   elem(r,k) = (r>>4)*512 + ((k&31)>>3)*128 + (r&15)*8 + (k&7)
#define A_HI   0
#define A_LO   2048
#define B_HI   4096
#define B_LO   12288
#define STG_TOT 20480            // ushorts = 40 KB -> 4 blocks/CU

// converted-weight limb size (ushorts): 128 steps x 8192
#define WQ_LIMB (NSG * 8192)

#define RT_TOK 16                // route tokens/block -> grid 1024, 4 blocks/CU

typedef __attribute__((ext_vector_type(8))) short bf16x8;
typedef __attribute__((ext_vector_type(4))) float f32x4;

__device__ __forceinline__ int stoffA(int r, int q) {
    return (r >> 4) * 512 + (q >> 1) * 128 + (r & 15) * 8 + (q & 1) * 4;
}
__device__ __forceinline__ int froffL(int lane) {
    return (lane >> 4) * 128 + (lane & 15) * 8;
}

// async global->LDS, 16 B per lane (R9-validated)
__device__ __forceinline__ void gload16(const void* g, void* l) {
    __builtin_amdgcn_global_load_lds(
        (const __attribute__((address_space(1))) void*)g,
        (__attribute__((address_space(3))) void*)l, 16, 0, 0);
}

// Split float4 into packed bf16 hi (RNE) and lo (RNE of exact residual).
__device__ __forceinline__ void split4(const float4 v, uint& h01, uint& h23,
                                       uint& l01, uint& l23) {
    const uint u0 = __float_as_uint(v.x) + 0x8000u;
    const uint u1 = __float_as_uint(v.y) + 0x8000u;
    const uint u2 = __float_as_uint(v.z) + 0x8000u;
    const uint u3 = __float_as_uint(v.w) + 0x8000u;
    h01 = __builtin_amdgcn_perm(u1, u0, 0x07060302u);
    h23 = __builtin_amdgcn_perm(u3, u2, 0x07060302u);
    const float f0 = v.x - __uint_as_float(u0 & 0xFFFF0000u);
    const float f1 = v.y - __uint_as_float(u1 & 0xFFFF0000u);
    const float f2 = v.z - __uint_as_float(u2 & 0xFFFF0000u);
    const float f3 = v.w - __uint_as_float(u3 & 0xFFFF0000u);
    l01 = __builtin_amdgcn_perm(__float_as_uint(f1) + 0x8000u,
                                __float_as_uint(f0) + 0x8000u, 0x07060302u);
    l23 = __builtin_amdgcn_perm(__float_as_uint(f3) + 0x8000u,
                                __float_as_uint(f2) + 0x8000u, 0x07060302u);
}

// ---- shared routing decision (identical in all paths; validated R5-R13) ----
template <class SC>
__device__ __forceinline__ bool route_core(SC sc, const float* __restrict__ bias,
                                           int* id, float* wv)
{
    float gs[NGROUP];
#pragma unroll
    for (int g = 0; g < NGROUP; ++g) {
        float m1 = -1e30f, m2 = -1e30f;
        for (int i = 0; i < GSIZE; ++i) {
            const int e = g * GSIZE + i;
            const float v = sc(e) + bias[e];
            if (v > m1)      { m2 = m1; m1 = v; }
            else if (v > m2) { m2 = v; }
        }
        gs[g] = m1 + m2;
    }

    unsigned gmask = 0;
    float g4 = -1e30f;
#pragma unroll
    for (int r = 0; r < TOPKG; ++r) {
        int bi = 0; float bv = -1e30f;
#pragma unroll
        for (int g = 0; g < NGROUP; ++g) {
            const bool taken = (gmask >> g) & 1;
            if (!taken && gs[g] > bv) { bv = gs[g]; bi = g; }
        }
        gmask |= 1u << bi;
        g4 = bv;
    }
    float g5 = -1e30f;
#pragma unroll
    for (int g = 0; g < NGROUP; ++g)
        if (!((gmask >> g) & 1) && gs[g] > g5) g5 = gs[g];

    float val[TOPK + 1]; int vid[TOPK + 1];
#pragma unroll
    for (int r = 0; r <= TOPK; ++r) { val[r] = -1e30f; vid[r] = 0; }
    for (int e = 0; e < NEXP; ++e) {
        const bool allowed = (gmask >> (e >> 5)) & 1;
        const float v = allowed ? (sc(e) + bias[e]) : 0.0f;
        if (v > val[TOPK]) {
#pragma unroll
            for (int p = TOPK; p >= 1; --p) {
                if (v > val[p - 1])  { val[p] = val[p - 1]; vid[p] = vid[p - 1]; }
                else if (v > val[p]) { val[p] = v;          vid[p] = e; }
            }
            if (v > val[0]) { val[0] = v; vid[0] = e; }
        }
    }

    bool tight = (g4 - g5 < TAUG);
#pragma unroll
    for (int i = 0; i < TOPK; ++i) tight |= (val[i] - val[i + 1] < TAU);

    float sum = 0.0f;
#pragma unroll
    for (int r = 0; r < TOPK; ++r) { id[r] = vid[r]; wv[r] = sc(vid[r]); sum += wv[r]; }
    const float inv = RSCALE / (sum + 1e-20f);
#pragma unroll
    for (int r = 0; r < TOPK; ++r) wv[r] *= inv;
    return tight;
}

// exact fp32 recompute + route for one token (cold fallback only)
__device__ void exact_token(const float* __restrict__ hs, const float* __restrict__ wt,
                            const float* __restrict__ bias, float* __restrict__ out, int t)
{
    float lg[NEXP];
    const float* hrow = hs + (size_t)t * HID;
    for (int e = 0; e < NEXP; ++e) {
        const float* wr = wt + (size_t)e * HID;
        float a = 0.0f;
        for (int k = 0; k < HID; k += 4) {
            const float4 x = *(const float4*)(hrow + k);
            const float4 b = *(const float4*)(wr + k);
            a = fmaf(x.x, b.x, a); a = fmaf(x.y, b.y, a);
            a = fmaf(x.z, b.z, a); a = fmaf(x.w, b.w, a);
        }
        lg[e] = 1.0f / (1.0f + expf(-a));
    }
    int id[TOPK]; float wv[TOPK];
    route_core([&](int e) { return lg[e]; }, bias, id, wv);
    for (int r = 0; r < TOPK; ++r) {
        out[(size_t)t * TOPK + r] = (float)id[r];
        out[(size_t)T_TOKENS * TOPK + (size_t)t * TOPK + r] = wv[r];
    }
}

// =============== one-shot weight conversion (R9-validated, unchanged) ===============
__global__ __launch_bounds__(256, 8)
void conv_weight(const float* __restrict__ wt, ushort* __restrict__ wq)
{
    const int g  = blockIdx.x * 256 + threadIdx.x;
    const int e  = g >> 9;
    const int kc = g & 511;
    const int sg  = kc >> 2;
    const int kch = kc & 3;

    const float4 v0 = *(const float4*)(wt + (size_t)e * HID + kc * 8);
    const float4 v1 = *(const float4*)(wt + (size_t)e * HID + kc * 8 + 4);
    uint h01, h23, l01, l23, h45, h67, l45, l67;
    split4(v0, h01, h23, l01, l23);
    split4(v1, h45, h67, l45, l67);

    const size_t idx = (size_t)sg * 8192 + (size_t)((e >> 4) * 512 + kch * 128 + (e & 15) * 8);
    uint4 hv; hv.x = h01; hv.y = h23; hv.z = h45; hv.w = h67;
    uint4 lv; lv.x = l01; lv.y = l23; lv.z = l45; lv.w = l67;
    *(uint4*)&wq[idx] = hv;
    *(uint4*)&wq[(size_t)WQ_LIMB + idx] = lv;
}

// =============== split-K GEMM v2 (R9-verbatim loop; XCD-local block swizzle) ===============
// block b -> (m, sk) s.t. an m-tile's 4 sk-slices land on the SAME XCD:
//   b = g*32 + s*8 + x  ->  m = g*8 + x, sk = s    (bijective, grid 1024)
__global__ __launch_bounds__(256, 4)
void router_gemm(const float* __restrict__ hs, const ushort* __restrict__ wq,
                 float* __restrict__ pw)
{
    __shared__ ushort u16[STG_TOT];

    const int tid  = threadIdx.x;
    const int lane = tid & 63;
    const int w    = tid >> 6;
    const int b    = blockIdx.x;
    const int m    = (b >> 5) * 8 + (b & 7);
    const int sk   = (b >> 3) & 3;
    const int t0   = m * BM;
    const int kb0  = sk * KSPAN;
    const int r0   = tid >> 3;           // 0..31
    const int q    = tid & 7;

    const ushort* wq_hi = wq;
    const ushort* wq_lo = wq + WQ_LIMB;

    f32x4 acc[4][4];
#pragma unroll
    for (int i = 0; i < 4; ++i)
#pragma unroll
        for (int j = 0; j < 4; ++j) acc[i][j] = (f32x4)0.0f;

    float4 ra[2];
#pragma unroll
    for (int s = 0; s < 2; ++s)
        ra[s] = *(const float4*)(hs + (size_t)(t0 + r0 + 32 * s) * HID + kb0 + q * 4);

    for (int ks = 0; ks < NKS; ++ks) {
        const int sg = sk * NKS + ks;
        __syncthreads();   // previous compute done; LDS reusable

        // ---- B: DMA pre-converted tiles (wave w stages its quarter) ----
        {
            const size_t gb = (size_t)sg * 8192 + (size_t)(w * 4) * 512 + (size_t)lane * 8;
#pragma unroll
            for (int i = 0; i < 4; ++i) {
                gload16(wq_hi + gb + i * 512, &u16[B_HI + (w * 4 + i) * 512]);
                gload16(wq_lo + gb + i * 512, &u16[B_LO + (w * 4 + i) * 512]);
            }
        }
        // ---- A: convert regs -> bf16 hi/lo, write frag-major LDS ----
#pragma unroll
        for (int s = 0; s < 2; ++s) {
            const int r = r0 + 32 * s;
            uint h01, h23, l01, l23;
            split4(ra[s], h01, h23, l01, l23);
            const int eo = stoffA(r, q);
            uint2 hv; hv.x = h01; hv.y = h23;
            uint2 lv; lv.x = l01; lv.y = l23;
            *(uint2*)&u16[A_HI + eo] = hv;
            *(uint2*)&u16[A_LO + eo] = lv;
        }
        __syncthreads();   // drains B DMA (vmcnt) + A writes visible

        // ---- prefetch next A K-step into regs ----
        if (ks + 1 < NKS) {
            const int kb = kb0 + (ks + 1) * BK;
#pragma unroll
            for (int s = 0; s < 2; ++s)
                ra[s] = *(const float4*)(hs + (size_t)(t0 + r0 + 32 * s) * HID + kb + q * 4);
        }

        // ---- compute: linear b128 frag reads (bank floor) + 48 MFMA/wave ----
        const int fo = froffL(lane);
        bf16x8 ah[4], al[4];
#pragma unroll
        for (int rt = 0; rt < 4; ++rt) {
            ah[rt] = *(const bf16x8*)&u16[A_HI + rt * 512 + fo];
            al[rt] = *(const bf16x8*)&u16[A_LO + rt * 512 + fo];
        }
#pragma unroll
        for (int c = 0; c < 4; ++c) {
            const int ct = w * 4 + c;
            const bf16x8 bh = *(const bf16x8*)&u16[B_HI + ct * 512 + fo];
            const bf16x8 bl = *(const bf16x8*)&u16[B_LO + ct * 512 + fo];
#pragma unroll
            for (int rt = 0; rt < 4; ++rt) {
                acc[rt][c] = __builtin_amdgcn_mfma_f32_16x16x32_bf16(ah[rt], bh, acc[rt][c], 0, 0, 0);
                acc[rt][c] = __builtin_amdgcn_mfma_f32_16x16x32_bf16(ah[rt], bl, acc[rt][c], 0, 0, 0);
                acc[rt][c] = __builtin_amdgcn_mfma_f32_16x16x32_bf16(al[rt], bh, acc[rt][c], 0, 0, 0);
            }
        }
    }

    // ---- store raw partial logits: pw[sk][token][expert] ----
#pragma unroll
    for (int rt = 0; rt < 4; ++rt)
#pragma unroll
        for (int c = 0; c < 4; ++c) {
            const int col  = w * 64 + c * 16 + (lane & 15);
            const int rowb = rt * 16 + (lane >> 4) * 4;
#pragma unroll
            for (int j = 0; j < 4; ++j)
                pw[((size_t)(sk * T_TOKENS) + t0 + rowb + j) * NEXP + col] = acc[rt][c][j];
        }
}

// =============== routing v2: 16 tokens/block, grid 1024 (4 blocks/CU) ===============
// block b_r -> m with m%8 == b_r%8 (same XCD as the gemm blocks that wrote pw[m])
__global__ __launch_bounds__(256, 4)
void router_route(const float* __restrict__ pw, const float* __restrict__ bias,
                  float* __restrict__ out,
                  unsigned* __restrict__ wcnt, unsigned* __restrict__ wlist,
                  unsigned cap)
{
    __shared__ float Lg[NEXP * RT_TOK];  // 16 KB
    const int tid  = threadIdx.x;
    const int b    = blockIdx.x;         // 1024
    const int x    = b & 7;
    const int rest = b >> 3;             // 0..127
    const int m    = (rest >> 2) * 8 + x;
    const int sub  = rest & 3;
    const int t0   = m * BM + sub * RT_TOK;

#pragma unroll
    for (int t = 0; t < RT_TOK; ++t) {
        float v = 0.0f;
#pragma unroll
        for (int s = 0; s < SPLITK; ++s)
            v += pw[((size_t)(s * T_TOKENS) + t0 + t) * NEXP + tid];
        Lg[tid * RT_TOK + ((t + tid) & (RT_TOK - 1))] = 1.0f / (1.0f + expf(-v));
    }
    __syncthreads();

    if (tid < RT_TOK) {
        const int t = t0 + tid;
        int id[TOPK]; float wv[TOPK];
        const bool tight = route_core(
            [&](int e) { return Lg[e * RT_TOK + ((tid + e) & (RT_TOK - 1))]; },
            bias, id, wv);

#pragma unroll
        for (int r = 0; r < TOPK; ++r) {
            out[(size_t)t * TOPK + r] = (float)id[r];
            out[(size_t)T_TOKENS * TOPK + (size_t)t * TOPK + r] = wv[r];
        }
        if (tight) {
            const unsigned pos = atomicAdd(wcnt, 1u);
            if (pos < cap) wlist[pos] = (unsigned)t;
        }
    }
}

// =============== cleanup v3 (R8-verbatim): one token per block, deep-issue ===============
__global__ __launch_bounds__(256, 4)
void router_exact(const float* __restrict__ hs, const float* __restrict__ wt,
                  const float* __restrict__ bias, float* __restrict__ out,
                  const unsigned* __restrict__ wcnt, const unsigned* __restrict__ wlist,
                  unsigned cap)
{
    __shared__ float hrow[HID];          // 16 KB
    __shared__ float lg[NEXP];           // 1 KB
    const unsigned count = min(*wcnt, cap);
    const int tid  = threadIdx.x;
    const int lane = tid & 63;
    const int w    = tid >> 6;

    for (unsigned b = blockIdx.x; b < count; b += gridDim.x) {
        __syncthreads();                 // guard hrow/lg reuse across passes
        const int t = (int)wlist[b];

#pragma unroll
        for (int i = 0; i < 4; ++i) {
            const int f4 = i * 256 + tid;
            *(float4*)&hrow[f4 * 4] = *(const float4*)(hs + (size_t)t * HID + f4 * 4);
        }
        __syncthreads();

        for (int g = 0; g < 16; ++g) {
            const int e0 = w * 64 + g * 4;
            float a[4] = {0.0f, 0.0f, 0.0f, 0.0f};
#pragma unroll 4
            for (int j = 0; j < 16; ++j) {
                const int f4 = j * 64 + lane;
                const float4 h = *(const float4*)&hrow[f4 * 4];
#pragma unroll
                for (int p = 0; p < 4; ++p) {
                    const float4 v = *(const float4*)(wt + (size_t)(e0 + p) * HID + f4 * 4);
                    a[p] = fmaf(h.x, v.x, a[p]); a[p] = fmaf(h.y, v.y, a[p]);
                    a[p] = fmaf(h.z, v.z, a[p]); a[p] = fmaf(h.w, v.w, a[p]);
                }
            }
#pragma unroll
            for (int p = 0; p < 4; ++p)
#pragma unroll
                for (int d = 1; d < 64; d <<= 1)
                    a[p] += __shfl_xor(a[p], d, 64);
            if (lane == 0) {
#pragma unroll
                for (int p = 0; p < 4; ++p)
                    lg[e0 + p] = 1.0f / (1.0f + expf(-a[p]));
            }
        }
        __syncthreads();

        if (tid == 0) {
            int id[TOPK]; float wv[TOPK];
            route_core([&](int e) { return lg[e]; }, bias, id, wv);
            for (int r = 0; r < TOPK; ++r) {
                out[(size_t)t * TOPK + r] = (float)id[r];
                out[(size_t)T_TOKENS * TOPK + (size_t)t * TOPK + r] = wv[r];
            }
        }
    }
}

// =============== fallback monolith (R5-validated, unchanged) ===============
__global__ __launch_bounds__(512, 1)
void router_mono(const float* __restrict__ hs, const float* __restrict__ wt,
                 const float* __restrict__ bias, float* __restrict__ out,
                 unsigned* __restrict__ wcnt, unsigned* __restrict__ wlist, unsigned cap)
{
    __shared__ float smem[16384];
    ushort* u16 = (ushort*)smem;
    float*  Lg  = smem;

    const int tid  = threadIdx.x;
    const int lane = tid & 63;
    const int w    = tid >> 6;
    const int t0   = blockIdx.x * 64;
    const int ar   = tid >> 3;
    const int aq   = tid & 7;

    f32x4 acc[4][2];
#pragma unroll
    for (int i = 0; i < 4; ++i)
#pragma unroll
        for (int j = 0; j < 2; ++j) acc[i][j] = (f32x4)0.0f;

    float4 ra, rb[4];
    ra = *(const float4*)(hs + (size_t)(t0 + ar) * HID + aq * 4);
#pragma unroll
    for (int s = 0; s < 4; ++s)
        rb[s] = *(const float4*)(wt + (size_t)(ar + s * 64) * HID + aq * 4);

    for (int ks = 0; ks < HID / BK; ++ks) {
        __syncthreads();
        {
            uint h01, h23, l01, l23;
            split4(ra, h01, h23, l01, l23);
            const int eo = stoffA(ar, aq);
            uint2 hv; hv.x = h01; hv.y = h23;
            uint2 lv; lv.x = l01; lv.y = l23;
            *(uint2*)&u16[0 + eo] = hv;
            *(uint2*)&u16[2048 + eo] = lv;
        }
#pragma unroll
        for (int s = 0; s < 4; ++s) {
            const int e = ar + s * 64;
            uint h01, h23, l01, l23;
            split4(rb[s], h01, h23, l01, l23);
            const int eo = stoffA(e, aq);
            uint2 hv; hv.x = h01; hv.y = h23;
            uint2 lv; lv.x = l01; lv.y = l23;
            *(uint2*)&u16[4096 + eo] = hv;
            *(uint2*)&u16[12288 + eo] = lv;
        }
        __syncthreads();
        if (ks + 1 < HID / BK) {
            const int k0 = (ks + 1) * BK;
            ra = *(const float4*)(hs + (size_t)(t0 + ar) * HID + k0 + aq * 4);
#pragma unroll
            for (int s = 0; s < 4; ++s)
                rb[s] = *(const float4*)(wt + (size_t)(ar + s * 64) * HID + k0 + aq * 4);
        }
        const int fo = froffL(lane);
        bf16x8 ah[4], al[4];
#pragma unroll
        for (int rt = 0; rt < 4; ++rt) {
            ah[rt] = *(const bf16x8*)&u16[0 + rt * 512 + fo];
            al[rt] = *(const bf16x8*)&u16[2048 + rt * 512 + fo];
        }
#pragma unroll
        for (int c = 0; c < 2; ++c) {
            const int ct = w * 2 + c;
            const bf16x8 bh = *(const bf16x8*)&u16[4096 + ct * 512 + fo];
            const bf16x8 bl = *(const bf16x8*)&u16[12288 + ct * 512 + fo];
#pragma unroll
            for (int rt = 0; rt < 4; ++rt) {
                acc[rt][c] = __builtin_amdgcn_mfma_f32_16x16x32_bf16(ah[rt], bh, acc[rt][c], 0, 0, 0);
                acc[rt][c] = __builtin_amdgcn_mfma_f32_16x16x32_bf16(ah[rt], bl, acc[rt][c], 0, 0, 0);
                acc[rt][c] = __builtin_amdgcn_mfma_f32_16x16x32_bf16(al[rt], bh, acc[rt][c], 0, 0, 0);
            }
        }
    }
    __syncthreads();
#pragma unroll
    for (int rt = 0; rt < 4; ++rt)
#pragma unroll
        for (int c = 0; c < 2; ++c) {
            const int col  = w * 32 + c * 16 + (lane & 15);
            const int rowb = rt * 16 + (lane >> 4) * 4;
#pragma unroll
            for (int j = 0; j < 4; ++j) {
                const int row = rowb + j;
                Lg[col * 64 + ((row + col) & 63)] = 1.0f / (1.0f + expf(-acc[rt][c][j]));
            }
        }
    __syncthreads();

    if (tid < 64) {
        const int t = t0 + tid;
        int id[TOPK]; float wv[TOPK];
        const bool tight = route_core(
            [&](int e) { return Lg[e * 64 + ((tid + e) & 63)]; }, bias, id, wv);
#pragma unroll
        for (int r = 0; r < TOPK; ++r) {
            out[(size_t)t * TOPK + r] = (float)id[r];
            out[(size_t)T_TOKENS * TOPK + (size_t)t * TOPK + r] = wv[r];
        }
        if (tight) {
            bool queued = false;
            if (wcnt) {
                const unsigned pos = atomicAdd(wcnt, 1u);
                if (pos < cap) { wlist[pos] = (unsigned)t; queued = true; }
            }
            if (!queued) exact_token(hs, wt, bias, out, t);
        }
    }
}

extern "C" void kernel_launch(void* const* d_in, const int* in_sizes, int n_in,
                              void* d_out, int out_size, void* d_ws, size_t ws_size,
                              hipStream_t stream) {
    const float* hs   = (const float*)d_in[0];   // [16384, 4096] f32
    const float* wt   = (const float*)d_in[1];   // [256, 4096]   f32
    const float* bias = (const float*)d_in[2];   // [256]         f32
    float* out = (float*)d_out;
    (void)in_sizes; (void)n_in; (void)out_size;

    const size_t PW_BYTES = (size_t)SPLITK * T_TOKENS * NEXP * 4;   // 64 MB
    const size_t WQ_BYTES = (size_t)2 * WQ_LIMB * 2;                // 4 MB
    const size_t NEED = PW_BYTES + WQ_BYTES + 4 + (size_t)T_TOKENS * 4;

    if (ws_size >= NEED) {
        float*    pw    = (float*)d_ws;
        ushort*   wq    = (ushort*)((char*)d_ws + PW_BYTES);
        unsigned* wcnt  = (unsigned*)((char*)d_ws + PW_BYTES + WQ_BYTES);
        unsigned* wlist = wcnt + 1;
        hipMemsetAsync(wcnt, 0, sizeof(unsigned), stream);
        conv_weight<<<512, 256, 0, stream>>>(wt, wq);
        router_gemm<<<(T_TOKENS / BM) * SPLITK, 256, 0, stream>>>(hs, wq, pw);
        router_route<<<T_TOKENS / RT_TOK, 256, 0, stream>>>(pw, bias, out, wcnt, wlist,
                                                            (unsigned)T_TOKENS);
        router_exact<<<2048, 256, 0, stream>>>(hs, wt, bias, out, wcnt, wlist,
                                               (unsigned)T_TOKENS);
    } else if (ws_size >= 8) {
        unsigned cap = (unsigned)((ws_size - 4) / 4);
        if (cap > T_TOKENS) cap = T_TOKENS;
        unsigned* wcnt  = (unsigned*)d_ws;
        unsigned* wlist = wcnt + 1;
        hipMemsetAsync(d_ws, 0, sizeof(unsigned), stream);
        router_mono<<<T_TOKENS / 64, 512, 0, stream>>>(hs, wt, bias, out, wcnt, wlist, cap);
        router_exact<<<2048, 256, 0, stream>>>(hs, wt, bias, out, wcnt, wlist, cap);
    } else {
        router_mono<<<T_TOKENS / 64, 512, 0, stream>>>(hs, wt, bias, out,
                                                       nullptr, nullptr, 0u);
    }
}

// Round 20
// 329.958 us; speedup vs baseline: 1.4669x; 1.0213x over previous
//
#include <hip/hip_runtime.h>
#include <math.h>

#define T_TOKENS 16384
#define HID      4096
#define NEXP     256
#define NGROUP   8
#define GSIZE    32
#define TOPKG    4
#define TOPK     8
#define RSCALE   2.5f

#define TAU   1.5e-5f    // expert-score margin (R13-validated)
#define TAUG  2.5e-5f    // group-score margin  (R13-validated)

// ---- split-K GEMM config (R9-validated) ----
#define BM     64
#define BK     32
#define SPLITK 4
#define KSPAN  (HID / SPLITK)    // 1024
#define NKS    (KSPAN / BK)      // 32 K-steps per block
#define NSG    (HID / BK)        // 128 global K-steps

// gemm LDS: A staging only (ushorts), frag-major (R9-validated):
//   elem(r,k) = (r>>4)*512 + ((k&31)>>3)*128 + (r&15)*8 + (k&7)
#define A_HI   0
#define A_LO   2048
#define A_TOT  4096              // ushorts = 8 KB

// converted-weight limb size (ushorts): 128 steps x 8192
#define WQ_LIMB (NSG * 8192)

#define RT_TOK 16                // route tokens/block -> grid 1024, 4 blocks/CU

typedef __attribute__((ext_vector_type(8))) short bf16x8;
typedef __attribute__((ext_vector_type(4))) float f32x4;

__device__ __forceinline__ int stoffA(int r, int q) {
    return (r >> 4) * 512 + (q >> 1) * 128 + (r & 15) * 8 + (q & 1) * 4;
}
__device__ __forceinline__ int froffL(int lane) {
    return (lane >> 4) * 128 + (lane & 15) * 8;
}

// Split float4 into packed bf16 hi (RNE) and lo (RNE of exact residual).
__device__ __forceinline__ void split4(const float4 v, uint& h01, uint& h23,
                                       uint& l01, uint& l23) {
    const uint u0 = __float_as_uint(v.x) + 0x8000u;
    const uint u1 = __float_as_uint(v.y) + 0x8000u;
    const uint u2 = __float_as_uint(v.z) + 0x8000u;
    const uint u3 = __float_as_uint(v.w) + 0x8000u;
    h01 = __builtin_amdgcn_perm(u1, u0, 0x07060302u);
    h23 = __builtin_amdgcn_perm(u3, u2, 0x07060302u);
    const float f0 = v.x - __uint_as_float(u0 & 0xFFFF0000u);
    const float f1 = v.y - __uint_as_float(u1 & 0xFFFF0000u);
    const float f2 = v.z - __uint_as_float(u2 & 0xFFFF0000u);
    const float f3 = v.w - __uint_as_float(u3 & 0xFFFF0000u);
    l01 = __builtin_amdgcn_perm(__float_as_uint(f1) + 0x8000u,
                                __float_as_uint(f0) + 0x8000u, 0x07060302u);
    l23 = __builtin_amdgcn_perm(__float_as_uint(f3) + 0x8000u,
                                __float_as_uint(f2) + 0x8000u, 0x07060302u);
}

// ---- shared routing decision (identical in all paths; validated R5-R19) ----
template <class SC>
__device__ __forceinline__ bool route_core(SC sc, const float* __restrict__ bias,
                                           int* id, float* wv)
{
    float gs[NGROUP];
#pragma unroll
    for (int g = 0; g < NGROUP; ++g) {
        float m1 = -1e30f, m2 = -1e30f;
        for (int i = 0; i < GSIZE; ++i) {
            const int e = g * GSIZE + i;
            const float v = sc(e) + bias[e];
            if (v > m1)      { m2 = m1; m1 = v; }
            else if (v > m2) { m2 = v; }
        }
        gs[g] = m1 + m2;
    }

    unsigned gmask = 0;
    float g4 = -1e30f;
#pragma unroll
    for (int r = 0; r < TOPKG; ++r) {
        int bi = 0; float bv = -1e30f;
#pragma unroll
        for (int g = 0; g < NGROUP; ++g) {
            const bool taken = (gmask >> g) & 1;
            if (!taken && gs[g] > bv) { bv = gs[g]; bi = g; }
        }
        gmask |= 1u << bi;
        g4 = bv;
    }
    float g5 = -1e30f;
#pragma unroll
    for (int g = 0; g < NGROUP; ++g)
        if (!((gmask >> g) & 1) && gs[g] > g5) g5 = gs[g];

    float val[TOPK + 1]; int vid[TOPK + 1];
#pragma unroll
    for (int r = 0; r <= TOPK; ++r) { val[r] = -1e30f; vid[r] = 0; }
    for (int e = 0; e < NEXP; ++e) {
        const bool allowed = (gmask >> (e >> 5)) & 1;
        const float v = allowed ? (sc(e) + bias[e]) : 0.0f;
        if (v > val[TOPK]) {
#pragma unroll
            for (int p = TOPK; p >= 1; --p) {
                if (v > val[p - 1])  { val[p] = val[p - 1]; vid[p] = vid[p - 1]; }
                else if (v > val[p]) { val[p] = v;          vid[p] = e; }
            }
            if (v > val[0]) { val[0] = v; vid[0] = e; }
        }
    }

    bool tight = (g4 - g5 < TAUG);
#pragma unroll
    for (int i = 0; i < TOPK; ++i) tight |= (val[i] - val[i + 1] < TAU);

    float sum = 0.0f;
#pragma unroll
    for (int r = 0; r < TOPK; ++r) { id[r] = vid[r]; wv[r] = sc(vid[r]); sum += wv[r]; }
    const float inv = RSCALE / (sum + 1e-20f);
#pragma unroll
    for (int r = 0; r < TOPK; ++r) wv[r] *= inv;
    return tight;
}

// exact fp32 recompute + route for one token (cold fallback only)
__device__ void exact_token(const float* __restrict__ hs, const float* __restrict__ wt,
                            const float* __restrict__ bias, float* __restrict__ out, int t)
{
    float lg[NEXP];
    const float* hrow = hs + (size_t)t * HID;
    for (int e = 0; e < NEXP; ++e) {
        const float* wr = wt + (size_t)e * HID;
        float a = 0.0f;
        for (int k = 0; k < HID; k += 4) {
            const float4 x = *(const float4*)(hrow + k);
            const float4 b = *(const float4*)(wr + k);
            a = fmaf(x.x, b.x, a); a = fmaf(x.y, b.y, a);
            a = fmaf(x.z, b.z, a); a = fmaf(x.w, b.w, a);
        }
        lg[e] = 1.0f / (1.0f + expf(-a));
    }
    int id[TOPK]; float wv[TOPK];
    route_core([&](int e) { return lg[e]; }, bias, id, wv);
    for (int r = 0; r < TOPK; ++r) {
        out[(size_t)t * TOPK + r] = (float)id[r];
        out[(size_t)T_TOKENS * TOPK + (size_t)t * TOPK + r] = wv[r];
    }
}

// =============== one-shot weight conversion (R9-validated, unchanged) ===============
__global__ __launch_bounds__(256, 8)
void conv_weight(const float* __restrict__ wt, ushort* __restrict__ wq)
{
    const int g  = blockIdx.x * 256 + threadIdx.x;
    const int e  = g >> 9;
    const int kc = g & 511;
    const int sg  = kc >> 2;
    const int kch = kc & 3;

    const float4 v0 = *(const float4*)(wt + (size_t)e * HID + kc * 8);
    const float4 v1 = *(const float4*)(wt + (size_t)e * HID + kc * 8 + 4);
    uint h01, h23, l01, l23, h45, h67, l45, l67;
    split4(v0, h01, h23, l01, l23);
    split4(v1, h45, h67, l45, l67);

    const size_t idx = (size_t)sg * 8192 + (size_t)((e >> 4) * 512 + kch * 128 + (e & 15) * 8);
    uint4 hv; hv.x = h01; hv.y = h23; hv.z = h45; hv.w = h67;
    uint4 lv; lv.x = l01; lv.y = l23; lv.z = l45; lv.w = l67;
    *(uint4*)&wq[idx] = hv;
    *(uint4*)&wq[(size_t)WQ_LIMB + idx] = lv;
}

// =============== split-K GEMM v5: A via LDS (R9 path), B DIRECT to VGPRs ===============
// B frags are per-lane contiguous 16B in frag-major wq (L2-resident) -> coalesced
// dwordx4 loads; removes B's DMA + 32 b128 LDS reads per block-step (LDS 40->8 KB).
// XCD-local swizzle (R14): b = g*32 + s*8 + x -> m = g*8 + x, sk = s.
__global__ __launch_bounds__(256, 4)
void router_gemm(const float* __restrict__ hs, const ushort* __restrict__ wq,
                 float* __restrict__ pw)
{
    __shared__ ushort u16[A_TOT];        // 8 KB, A staging only

    const int tid  = threadIdx.x;
    const int lane = tid & 63;
    const int w    = tid >> 6;
    const int b    = blockIdx.x;
    const int m    = (b >> 5) * 8 + (b & 7);
    const int sk   = (b >> 3) & 3;
    const int t0   = m * BM;
    const int kb0  = sk * KSPAN;
    const int r0   = tid >> 3;           // 0..31
    const int q    = tid & 7;

    const ushort* wq_hi = wq;
    const ushort* wq_lo = wq + WQ_LIMB;

    f32x4 acc[4][4];
#pragma unroll
    for (int i = 0; i < 4; ++i)
#pragma unroll
        for (int j = 0; j < 4; ++j) acc[i][j] = (f32x4)0.0f;

    float4 ra[2];
#pragma unroll
    for (int s = 0; s < 2; ++s)
        ra[s] = *(const float4*)(hs + (size_t)(t0 + r0 + 32 * s) * HID + kb0 + q * 4);

    for (int ks = 0; ks < NKS; ++ks) {
        const int sg = sk * NKS + ks;
        __syncthreads();   // previous compute done; A LDS reusable

        // ---- A: convert regs -> bf16 hi/lo, write frag-major LDS ----
#pragma unroll
        for (int s = 0; s < 2; ++s) {
            const int r = r0 + 32 * s;
            uint h01, h23, l01, l23;
            split4(ra[s], h01, h23, l01, l23);
            const int eo = stoffA(r, q);
            uint2 hv; hv.x = h01; hv.y = h23;
            uint2 lv; lv.x = l01; lv.y = l23;
            *(uint2*)&u16[A_HI + eo] = hv;
            *(uint2*)&u16[A_LO + eo] = lv;
        }
        __syncthreads();   // A tile visible

        // ---- B: direct per-lane frag loads from L2-resident wq (coalesced 16B) ----
        bf16x8 bh[4], bl[4];
        {
            const size_t bb = (size_t)sg * 8192 + (size_t)(w * 4) * 512 + (size_t)lane * 8;
#pragma unroll
            for (int c = 0; c < 4; ++c) {
                bh[c] = *(const bf16x8*)(wq_hi + bb + c * 512);
                bl[c] = *(const bf16x8*)(wq_lo + bb + c * 512);
            }
        }
        // ---- prefetch next A K-step into regs ----
        if (ks + 1 < NKS) {
            const int kb = kb0 + (ks + 1) * BK;
#pragma unroll
            for (int s = 0; s < 2; ++s)
                ra[s] = *(const float4*)(hs + (size_t)(t0 + r0 + 32 * s) * HID + kb + q * 4);
        }

        // ---- A frags (linear b128, bank floor) + 48 MFMA/wave ----
        const int fo = froffL(lane);
        bf16x8 ah[4], al[4];
#pragma unroll
        for (int rt = 0; rt < 4; ++rt) {
            ah[rt] = *(const bf16x8*)&u16[A_HI + rt * 512 + fo];
            al[rt] = *(const bf16x8*)&u16[A_LO + rt * 512 + fo];
        }
#pragma unroll
        for (int c = 0; c < 4; ++c) {
#pragma unroll
            for (int rt = 0; rt < 4; ++rt) {
                acc[rt][c] = __builtin_amdgcn_mfma_f32_16x16x32_bf16(ah[rt], bh[c], acc[rt][c], 0, 0, 0);
                acc[rt][c] = __builtin_amdgcn_mfma_f32_16x16x32_bf16(ah[rt], bl[c], acc[rt][c], 0, 0, 0);
                acc[rt][c] = __builtin_amdgcn_mfma_f32_16x16x32_bf16(al[rt], bh[c], acc[rt][c], 0, 0, 0);
            }
        }
    }

    // ---- store raw partial logits: pw[sk][token][expert] ----
#pragma unroll
    for (int rt = 0; rt < 4; ++rt)
#pragma unroll
        for (int c = 0; c < 4; ++c) {
            const int col  = w * 64 + c * 16 + (lane & 15);
            const int rowb = rt * 16 + (lane >> 4) * 4;
#pragma unroll
            for (int j = 0; j < 4; ++j)
                pw[((size_t)(sk * T_TOKENS) + t0 + rowb + j) * NEXP + col] = acc[rt][c][j];
        }
}

// =============== routing v2: 16 tokens/block, grid 1024 (4 blocks/CU) ===============
// block b_r -> m with m%8 == b_r%8 (same XCD as the gemm blocks that wrote pw[m])
__global__ __launch_bounds__(256, 4)
void router_route(const float* __restrict__ pw, const float* __restrict__ bias,
                  float* __restrict__ out,
                  unsigned* __restrict__ wcnt, unsigned* __restrict__ wlist,
                  unsigned cap)
{
    __shared__ float Lg[NEXP * RT_TOK];  // 16 KB
    const int tid  = threadIdx.x;
    const int b    = blockIdx.x;         // 1024
    const int x    = b & 7;
    const int rest = b >> 3;             // 0..127
    const int m    = (rest >> 2) * 8 + x;
    const int sub  = rest & 3;
    const int t0   = m * BM + sub * RT_TOK;

#pragma unroll
    for (int t = 0; t < RT_TOK; ++t) {
        float v = 0.0f;
#pragma unroll
        for (int s = 0; s < SPLITK; ++s)
            v += pw[((size_t)(s * T_TOKENS) + t0 + t) * NEXP + tid];
        Lg[tid * RT_TOK + ((t + tid) & (RT_TOK - 1))] = 1.0f / (1.0f + expf(-v));
    }
    __syncthreads();

    if (tid < RT_TOK) {
        const int t = t0 + tid;
        int id[TOPK]; float wv[TOPK];
        const bool tight = route_core(
            [&](int e) { return Lg[e * RT_TOK + ((tid + e) & (RT_TOK - 1))]; },
            bias, id, wv);

#pragma unroll
        for (int r = 0; r < TOPK; ++r) {
            out[(size_t)t * TOPK + r] = (float)id[r];
            out[(size_t)T_TOKENS * TOPK + (size_t)t * TOPK + r] = wv[r];
        }
        if (tight) {
            const unsigned pos = atomicAdd(wcnt, 1u);
            if (pos < cap) wlist[pos] = (unsigned)t;
        }
    }
}

// =============== cleanup v3 (R8-verbatim): one token per block, deep-issue ===============
__global__ __launch_bounds__(256, 4)
void router_exact(const float* __restrict__ hs, const float* __restrict__ wt,
                  const float* __restrict__ bias, float* __restrict__ out,
                  const unsigned* __restrict__ wcnt, const unsigned* __restrict__ wlist,
                  unsigned cap)
{
    __shared__ float hrow[HID];          // 16 KB
    __shared__ float lg[NEXP];           // 1 KB
    const unsigned count = min(*wcnt, cap);
    const int tid  = threadIdx.x;
    const int lane = tid & 63;
    const int w    = tid >> 6;

    for (unsigned b = blockIdx.x; b < count; b += gridDim.x) {
        __syncthreads();                 // guard hrow/lg reuse across passes
        const int t = (int)wlist[b];

#pragma unroll
        for (int i = 0; i < 4; ++i) {
            const int f4 = i * 256 + tid;
            *(float4*)&hrow[f4 * 4] = *(const float4*)(hs + (size_t)t * HID + f4 * 4);
        }
        __syncthreads();

        for (int g = 0; g < 16; ++g) {
            const int e0 = w * 64 + g * 4;
            float a[4] = {0.0f, 0.0f, 0.0f, 0.0f};
#pragma unroll 4
            for (int j = 0; j < 16; ++j) {
                const int f4 = j * 64 + lane;
                const float4 h = *(const float4*)&hrow[f4 * 4];
#pragma unroll
                for (int p = 0; p < 4; ++p) {
                    const float4 v = *(const float4*)(wt + (size_t)(e0 + p) * HID + f4 * 4);
                    a[p] = fmaf(h.x, v.x, a[p]); a[p] = fmaf(h.y, v.y, a[p]);
                    a[p] = fmaf(h.z, v.z, a[p]); a[p] = fmaf(h.w, v.w, a[p]);
                }
            }
#pragma unroll
            for (int p = 0; p < 4; ++p)
#pragma unroll
                for (int d = 1; d < 64; d <<= 1)
                    a[p] += __shfl_xor(a[p], d, 64);
            if (lane == 0) {
#pragma unroll
                for (int p = 0; p < 4; ++p)
                    lg[e0 + p] = 1.0f / (1.0f + expf(-a[p]));
            }
        }
        __syncthreads();

        if (tid == 0) {
            int id[TOPK]; float wv[TOPK];
            route_core([&](int e) { return lg[e]; }, bias, id, wv);
            for (int r = 0; r < TOPK; ++r) {
                out[(size_t)t * TOPK + r] = (float)id[r];
                out[(size_t)T_TOKENS * TOPK + (size_t)t * TOPK + r] = wv[r];
            }
        }
    }
}

// =============== fallback monolith (R5-validated, unchanged) ===============
__global__ __launch_bounds__(512, 1)
void router_mono(const float* __restrict__ hs, const float* __restrict__ wt,
                 const float* __restrict__ bias, float* __restrict__ out,
                 unsigned* __restrict__ wcnt, unsigned* __restrict__ wlist, unsigned cap)
{
    __shared__ float smem[16384];
    ushort* u16 = (ushort*)smem;
    float*  Lg  = smem;

    const int tid  = threadIdx.x;
    const int lane = tid & 63;
    const int w    = tid >> 6;
    const int t0   = blockIdx.x * 64;
    const int ar   = tid >> 3;
    const int aq   = tid & 7;

    f32x4 acc[4][2];
#pragma unroll
    for (int i = 0; i < 4; ++i)
#pragma unroll
        for (int j = 0; j < 2; ++j) acc[i][j] = (f32x4)0.0f;

    float4 ra, rb[4];
    ra = *(const float4*)(hs + (size_t)(t0 + ar) * HID + aq * 4);
#pragma unroll
    for (int s = 0; s < 4; ++s)
        rb[s] = *(const float4*)(wt + (size_t)(ar + s * 64) * HID + aq * 4);

    for (int ks = 0; ks < HID / BK; ++ks) {
        __syncthreads();
        {
            uint h01, h23, l01, l23;
            split4(ra, h01, h23, l01, l23);
            const int eo = stoffA(ar, aq);
            uint2 hv; hv.x = h01; hv.y = h23;
            uint2 lv; lv.x = l01; lv.y = l23;
            *(uint2*)&u16[0 + eo] = hv;
            *(uint2*)&u16[2048 + eo] = lv;
        }
#pragma unroll
        for (int s = 0; s < 4; ++s) {
            const int e = ar + s * 64;
            uint h01, h23, l01, l23;
            split4(rb[s], h01, h23, l01, l23);
            const int eo = stoffA(e, aq);
            uint2 hv; hv.x = h01; hv.y = h23;
            uint2 lv; lv.x = l01; lv.y = l23;
            *(uint2*)&u16[4096 + eo] = hv;
            *(uint2*)&u16[12288 + eo] = lv;
        }
        __syncthreads();
        if (ks + 1 < HID / BK) {
            const int k0 = (ks + 1) * BK;
            ra = *(const float4*)(hs + (size_t)(t0 + ar) * HID + k0 + aq * 4);
#pragma unroll
            for (int s = 0; s < 4; ++s)
                rb[s] = *(const float4*)(wt + (size_t)(ar + s * 64) * HID + k0 + aq * 4);
        }
        const int fo = froffL(lane);
        bf16x8 ah[4], al[4];
#pragma unroll
        for (int rt = 0; rt < 4; ++rt) {
            ah[rt] = *(const bf16x8*)&u16[0 + rt * 512 + fo];
            al[rt] = *(const bf16x8*)&u16[2048 + rt * 512 + fo];
        }
#pragma unroll
        for (int c = 0; c < 2; ++c) {
            const int ct = w * 2 + c;
            const bf16x8 bh = *(const bf16x8*)&u16[4096 + ct * 512 + fo];
            const bf16x8 bl = *(const bf16x8*)&u16[12288 + ct * 512 + fo];
#pragma unroll
            for (int rt = 0; rt < 4; ++rt) {
                acc[rt][c] = __builtin_amdgcn_mfma_f32_16x16x32_bf16(ah[rt], bh, acc[rt][c], 0, 0, 0);
                acc[rt][c] = __builtin_amdgcn_mfma_f32_16x16x32_bf16(ah[rt], bl, acc[rt][c], 0, 0, 0);
                acc[rt][c] = __builtin_amdgcn_mfma_f32_16x16x32_bf16(al[rt], bh, acc[rt][c], 0, 0, 0);
            }
        }
    }
    __syncthreads();
#pragma unroll
    for (int rt = 0; rt < 4; ++rt)
#pragma unroll
        for (int c = 0; c < 2; ++c) {
            const int col  = w * 32 + c * 16 + (lane & 15);
            const int rowb = rt * 16 + (lane >> 4) * 4;
#pragma unroll
            for (int j = 0; j < 4; ++j) {
                const int row = rowb + j;
                Lg[col * 64 + ((row + col) & 63)] = 1.0f / (1.0f + expf(-acc[rt][c][j]));
            }
        }
    __syncthreads();

    if (tid < 64) {
        const int t = t0 + tid;
        int id[TOPK]; float wv[TOPK];
        const bool tight = route_core(
            [&](int e) { return Lg[e * 64 + ((tid + e) & 63)]; }, bias, id, wv);
#pragma unroll
        for (int r = 0; r < TOPK; ++r) {
            out[(size_t)t * TOPK + r] = (float)id[r];
            out[(size_t)T_TOKENS * TOPK + (size_t)t * TOPK + r] = wv[r];
        }
        if (tight) {
            bool queued = false;
            if (wcnt) {
                const unsigned pos = atomicAdd(wcnt, 1u);
                if (pos < cap) { wlist[pos] = (unsigned)t; queued = true; }
            }
            if (!queued) exact_token(hs, wt, bias, out, t);
        }
    }
}

extern "C" void kernel_launch(void* const* d_in, const int* in_sizes, int n_in,
                              void* d_out, int out_size, void* d_ws, size_t ws_size,
                              hipStream_t stream) {
    const float* hs   = (const float*)d_in[0];   // [16384, 4096] f32
    const float* wt   = (const float*)d_in[1];   // [256, 4096]   f32
    const float* bias = (const float*)d_in[2];   // [256]         f32
    float* out = (float*)d_out;
    (void)in_sizes; (void)n_in; (void)out_size;

    const size_t PW_BYTES = (size_t)SPLITK * T_TOKENS * NEXP * 4;   // 64 MB
    const size_t WQ_BYTES = (size_t)2 * WQ_LIMB * 2;                // 4 MB
    const size_t NEED = PW_BYTES + WQ_BYTES + 4 + (size_t)T_TOKENS * 4;

    if (ws_size >= NEED) {
        float*    pw    = (float*)d_ws;
        ushort*   wq    = (ushort*)((char*)d_ws + PW_BYTES);
        unsigned* wcnt  = (unsigned*)((char*)d_ws + PW_BYTES + WQ_BYTES);
        unsigned* wlist = wcnt + 1;
        hipMemsetAsync(wcnt, 0, sizeof(unsigned), stream);
        conv_weight<<<512, 256, 0, stream>>>(wt, wq);
        router_gemm<<<(T_TOKENS / BM) * SPLITK, 256, 0, stream>>>(hs, wq, pw);
        router_route<<<T_TOKENS / RT_TOK, 256, 0, stream>>>(pw, bias, out, wcnt, wlist,
                                                            (unsigned)T_TOKENS);
        router_exact<<<2048, 256, 0, stream>>>(hs, wt, bias, out, wcnt, wlist,
                                               (unsigned)T_TOKENS);
    } else if (ws_size >= 8) {
        unsigned cap = (unsigned)((ws_size - 4) / 4);
        if (cap > T_TOKENS) cap = T_TOKENS;
        unsigned* wcnt  = (unsigned*)d_ws;
        unsigned* wlist = wcnt + 1;
        hipMemsetAsync(d_ws, 0, sizeof(unsigned), stream);
        router_mono<<<T_TOKENS / 64, 512, 0, stream>>>(hs, wt, bias, out, wcnt, wlist, cap);
        router_exact<<<2048, 256, 0, stream>>>(hs, wt, bias, out, wcnt, wlist, cap);
    } else {
        router_mono<<<T_TOKENS / 64, 512, 0, stream>>>(hs, wt, bias, out,
                                                       nullptr, nullptr, 0u);
    }
}